// Round 2
// baseline (240.578 us; speedup 1.0000x reference)
//
#include <hip/hip_runtime.h>
#include <hip/hip_bf16.h>

typedef __hip_bfloat16 bf16;
using f4 = __attribute__((ext_vector_type(4))) float;
using s8 = __attribute__((ext_vector_type(8))) short;
using s4 = __attribute__((ext_vector_type(4))) short;

__device__ __forceinline__ void storeOut(float* p, float v) { *p = v; }
__device__ __forceinline__ void storeOut(bf16* p, float v) { *p = __float2bfloat16(v); }
__device__ __forceinline__ short bfs(float x) { return __builtin_bit_cast(short, __float2bfloat16(x)); }

constexpr int B_ = 4, T_ = 1024, M_ = 256, C_ = 512, H_ = 8, HD_ = 64, C3_ = 1536;

#define MFMA16(a, b, c) __builtin_amdgcn_mfma_f32_16x16x32_bf16((a), (b), (c), 0, 0, 0)

// ---------------- prep: 5 weight transposes (fp32 KxN -> bf16 NxK) + 2 converts ----------------
__global__ __launch_bounds__(256) void prep_kernel(
    const float* __restrict__ Wqkv_x, const float* __restrict__ Wqkv_y,
    const float* __restrict__ Wgs, const float* __restrict__ Wgc, const float* __restrict__ Wp,
    const float* __restrict__ x, const float* __restrict__ y,
    bf16* __restrict__ WT_x, bf16* __restrict__ WT_y, bf16* __restrict__ WT_gs,
    bf16* __restrict__ WT_gc, bf16* __restrict__ WT_p,
    bf16* __restrict__ x_bf, bf16* __restrict__ y_bf)
{
    __shared__ float Ls[64][65];
    const int tid = threadIdx.x;
    const int bid = blockIdx.x;
    if (bid < 576) {
        const float* W; bf16* WT; int N, t;
        if (bid < 192)      { W = Wqkv_x; WT = WT_x;  N = C3_; t = bid; }
        else if (bid < 384) { W = Wqkv_y; WT = WT_y;  N = C3_; t = bid - 192; }
        else if (bid < 448) { W = Wgs;    WT = WT_gs; N = C_;  t = bid - 384; }
        else if (bid < 512) { W = Wgc;    WT = WT_gc; N = C_;  t = bid - 448; }
        else                { W = Wp;     WT = WT_p;  N = C_;  t = bid - 512; }
        const int K = C_;
        const int tw = N >> 6;
        const int n0 = (t % tw) * 64, k0 = (t / tw) * 64;
        for (int i = tid; i < 1024; i += 256) {
            int kr = i >> 4, ng = i & 15;
            float4 v = *(const float4*)&W[(size_t)(k0 + kr) * N + n0 + ng * 4];
            Ls[ng * 4 + 0][kr] = v.x; Ls[ng * 4 + 1][kr] = v.y;
            Ls[ng * 4 + 2][kr] = v.z; Ls[ng * 4 + 3][kr] = v.w;
        }
        __syncthreads();
        for (int i = tid; i < 512; i += 256) {
            int n = i >> 3, kg = i & 7;
            s8 r;
            #pragma unroll
            for (int j = 0; j < 8; ++j) r[j] = bfs(Ls[n][kg * 8 + j]);
            *(s8*)&WT[(size_t)(n0 + n) * K + k0 + kg * 8] = r;
        }
    } else if (bid < 1600) {
        int i = (bid - 576) * 2048 + tid * 8;
        s8 r;
        #pragma unroll
        for (int j = 0; j < 8; ++j) r[j] = bfs(x[i + j]);
        *(s8*)&x_bf[i] = r;
    } else {
        int i = (bid - 1600) * 2048 + tid * 8;
        s8 r;
        #pragma unroll
        for (int j = 0; j < 8; ++j) r[j] = bfs(y[i + j]);
        *(s8*)&y_bf[i] = r;
    }
}

// ---------------- merged catt1/catt2 + qw (one dispatch) ----------------
__global__ __launch_bounds__(256) void qwcatt_kernel(
    const bf16* __restrict__ qkv_x, const bf16* __restrict__ qkv_y,
    const float* __restrict__ w4x, const float* __restrict__ w4y,
    const float* __restrict__ w4xy,
    float* __restrict__ catt1b, float* __restrict__ catt2b, bf16* __restrict__ qw)
{
    const int bid = blockIdx.x;
    const int tid = threadIdx.x;
    if (bid < 160) {
        int i = bid * 256 + tid;   // 0..40959
        const bf16* row; const float* w; float* out; int oi;
        if (i < 32768) {
            int bh = i >> 10, t = i & 1023, b = bh >> 3, h = bh & 7;
            row = qkv_x + (size_t)(b * T_ + t) * C3_ + h * HD_;
            w = w4x + h * HD_; out = catt1b; oi = i;
        } else {
            int j = i - 32768;
            int bh = j >> 8, m = j & 255, b = bh >> 3, h = bh & 7;
            row = qkv_y + (size_t)(b * M_ + m) * C3_ + h * HD_;
            w = w4y + h * HD_; out = catt2b; oi = j;
        }
        float s = 0.f;
        #pragma unroll
        for (int d = 0; d < HD_; ++d) s = fmaf(__bfloat162float(row[d]), w[d], s);
        out[oi] = s;
    } else {
        int o = ((bid - 160) * 256 + tid) * 8;
        int row = o >> 9, c = o & 511;
        const bf16* src = qkv_x + (size_t)row * C3_ + c;
        s8 r;
        #pragma unroll
        for (int j = 0; j < 8; ++j) r[j] = bfs(__bfloat162float(src[j]) * w4xy[c + j]);
        *(s8*)&qw[o] = r;
    }
}

// ---------------- LDS-staged MFMA GEMM (m-major grid) ----------------
template <typename OT>
__global__ __launch_bounds__(256) void gemm_staged_kernel(
    const bf16* __restrict__ A, const bf16* __restrict__ WT, const float* __restrict__ bias,
    OT* __restrict__ Cmat, int N, int K)
{
    __shared__ short Asb[128][72];
    __shared__ short Bsb[64][72];
    const int tid = threadIdx.x;
    const int wave = tid >> 6, lane = tid & 63;
    const int quad = lane >> 4, l16 = lane & 15;
    const int n0 = blockIdx.y * 64, m0 = blockIdx.x * 128;
    f4 acc[2][4];
    #pragma unroll
    for (int mt = 0; mt < 2; ++mt)
        #pragma unroll
        for (int nt = 0; nt < 4; ++nt) acc[mt][nt] = (f4)0.f;

    for (int k0 = 0; k0 < K; k0 += 64) {
        #pragma unroll
        for (int tl = 0; tl < 4; ++tl) {
            int g = tid + tl * 256, row = g >> 3, grp = g & 7;
            *(s8*)&Asb[row][grp * 8] = *(const s8*)&A[(size_t)(m0 + row) * K + k0 + grp * 8];
        }
        #pragma unroll
        for (int tl = 0; tl < 2; ++tl) {
            int g = tid + tl * 256, n = g >> 3, grp = g & 7;
            *(s8*)&Bsb[n][grp * 8] = *(const s8*)&WT[(size_t)(n0 + n) * K + k0 + grp * 8];
        }
        __syncthreads();
        #pragma unroll
        for (int ks = 0; ks < 2; ++ks) {
            s8 a0 = *(const s8*)&Asb[wave * 32 + l16][ks * 32 + quad * 8];
            s8 a1 = *(const s8*)&Asb[wave * 32 + 16 + l16][ks * 32 + quad * 8];
            #pragma unroll
            for (int nt = 0; nt < 4; ++nt) {
                s8 bv = *(const s8*)&Bsb[nt * 16 + l16][ks * 32 + quad * 8];
                acc[0][nt] = MFMA16(a0, bv, acc[0][nt]);
                acc[1][nt] = MFMA16(a1, bv, acc[1][nt]);
            }
        }
        __syncthreads();
    }
    #pragma unroll
    for (int mt = 0; mt < 2; ++mt)
        #pragma unroll
        for (int nt = 0; nt < 4; ++nt) {
            int col = n0 + nt * 16 + l16;
            float bb = bias[col];
            #pragma unroll
            for (int reg = 0; reg < 4; ++reg) {
                int row = m0 + wave * 32 + mt * 16 + quad * 4 + reg;
                storeOut(&Cmat[(size_t)row * N + col], acc[mt][nt][reg] + bb);
            }
        }
}

// ---------------- catt3r: logits + row softmax -> x2y bf16 + rowsum + col partial sums ----------------
__global__ __launch_bounds__(256) void catt3r_kernel(
    const bf16* __restrict__ qw, const bf16* __restrict__ qkv_y,
    const float* __restrict__ catt1, const float* __restrict__ catt2,
    bf16* __restrict__ x2y, float* __restrict__ rowsum_, float* __restrict__ psum)
{
    __shared__ float redc[4][256];
    const int tid = threadIdx.x;
    const int wave = tid >> 6, lane = tid & 63;
    const int quad = lane >> 4, l16 = lane & 15;
    const int bh = blockIdx.x, b = bh >> 3, h = bh & 7;
    const int t0 = blockIdx.y * 64;
    f4 sc[4][4];
    #pragma unroll
    for (int mt = 0; mt < 4; ++mt)
        #pragma unroll
        for (int nt = 0; nt < 4; ++nt) sc[mt][nt] = (f4)0.f;

    const bf16* ap = qw + (size_t)(b * T_ + t0 + wave * 16 + l16) * C_ + h * HD_ + quad * 8;
    s8 a0 = *(const s8*)ap;
    s8 a1 = *(const s8*)(ap + 32);
    const bf16* bp = qkv_y + (size_t)(b * M_ + l16) * C3_ + C_ + h * HD_ + quad * 8;
    #pragma unroll
    for (int mt = 0; mt < 4; ++mt)
        #pragma unroll
        for (int nt = 0; nt < 4; ++nt) {
            const bf16* bq = bp + (size_t)(mt * 64 + nt * 16) * C3_;
            sc[mt][nt] = MFMA16(a0, *(const s8*)bq, sc[mt][nt]);
            sc[mt][nt] = MFMA16(a1, *(const s8*)(bq + 32), sc[mt][nt]);
        }

    float c1[4];
    #pragma unroll
    for (int reg = 0; reg < 4; ++reg)
        c1[reg] = catt1[bh * T_ + t0 + wave * 16 + quad * 4 + reg];
    #pragma unroll
    for (int mt = 0; mt < 4; ++mt)
        #pragma unroll
        for (int nt = 0; nt < 4; ++nt) {
            float c2 = catt2[bh * M_ + mt * 64 + nt * 16 + l16];
            #pragma unroll
            for (int reg = 0; reg < 4; ++reg)
                sc[mt][nt][reg] = __expf(sc[mt][nt][reg] * 0.125f + c1[reg] + c2);
        }

    #pragma unroll
    for (int reg = 0; reg < 4; ++reg) {
        float rs = 0.f;
        #pragma unroll
        for (int mt = 0; mt < 4; ++mt)
            #pragma unroll
            for (int nt = 0; nt < 4; ++nt) rs += sc[mt][nt][reg];
        rs += __shfl_xor(rs, 1); rs += __shfl_xor(rs, 2);
        rs += __shfl_xor(rs, 4); rs += __shfl_xor(rs, 8);
        const int t = t0 + wave * 16 + quad * 4 + reg;
        if (l16 == 0) rowsum_[bh * T_ + t] = rs;
        const float ri = 1.f / rs;
        #pragma unroll
        for (int mt = 0; mt < 4; ++mt)
            #pragma unroll
            for (int nt = 0; nt < 4; ++nt)
                x2y[((size_t)bh * T_ + t) * M_ + mt * 64 + nt * 16 + l16] =
                    __float2bfloat16(sc[mt][nt][reg] * ri);
    }

    #pragma unroll
    for (int mt = 0; mt < 4; ++mt)
        #pragma unroll
        for (int nt = 0; nt < 4; ++nt) {
            float es = sc[mt][nt][0] + sc[mt][nt][1] + sc[mt][nt][2] + sc[mt][nt][3];
            es += __shfl_xor(es, 16);
            es += __shfl_xor(es, 32);
            if (quad == 0) redc[wave][mt * 64 + nt * 16 + l16] = es;
        }
    __syncthreads();
    psum[((size_t)bh * 16 + blockIdx.y) * M_ + tid] =
        redc[0][tid] + redc[1][tid] + redc[2][tid] + redc[3][tid];
}

// ---------------- merged colfin + V transposes (one dispatch) ----------------
__global__ __launch_bounds__(256) void colfin_vtrans_kernel(
    const float* __restrict__ psum, float* __restrict__ colinv,
    const bf16* __restrict__ qkv_x, const bf16* __restrict__ qkv_y,
    bf16* __restrict__ vTx, bf16* __restrict__ vTy)
{
    __shared__ short Ls[64][68];
    const int tid = threadIdx.x;
    int bid = blockIdx.x;
    if (bid < 32) {
        const int bh = bid, m = tid;
        float s = 0.f;
        #pragma unroll
        for (int ch = 0; ch < 16; ++ch) s += psum[(bh * 16 + ch) * M_ + m];
        colinv[bh * M_ + m] = 1.f / s;
        return;
    }
    bid -= 32;
    const bf16* qkv; bf16* vT; int Nrows, bh, t0;
    if (bid < 512) { qkv = qkv_x; vT = vTx; Nrows = T_; bh = bid >> 4; t0 = (bid & 15) * 64; }
    else { bid -= 512; qkv = qkv_y; vT = vTy; Nrows = M_; bh = bid >> 2; t0 = (bid & 3) * 64; }
    const int b = bh >> 3, h = bh & 7;
    for (int i = tid; i < 4096; i += 256) {
        int tl = i >> 6, d = i & 63;
        Ls[d][tl] = __builtin_bit_cast(short,
            qkv[(size_t)(b * Nrows + t0 + tl) * C3_ + 2 * C_ + h * HD_ + d]);
    }
    __syncthreads();
    for (int i = tid; i < 4096; i += 256) {
        int d = i >> 6, tl = i & 63;
        vT[((size_t)bh * 64 + d) * Nrows + t0 + tl] = __builtin_bit_cast(bf16, Ls[d][tl]);
    }
}

// ---------------- y2xw: y2x = x2y * rowsum * colinv ----------------
__global__ __launch_bounds__(256) void y2xw_kernel(
    const bf16* __restrict__ x2y, const float* __restrict__ rowsum_,
    const float* __restrict__ colinv, bf16* __restrict__ y2x)
{
    const int i = (blockIdx.x * 256 + threadIdx.x) * 8;
    const int row = i >> 8, m = i & 255, bh = row >> 10;
    const float rs = rowsum_[row];
    s8 v = *(const s8*)&x2y[i];
    const float4 c0 = *(const float4*)&colinv[bh * M_ + m];
    const float4 c4 = *(const float4*)&colinv[bh * M_ + m + 4];
    float ci[8] = {c0.x, c0.y, c0.z, c0.w, c4.x, c4.y, c4.z, c4.w};
    s8 r;
    #pragma unroll
    for (int j = 0; j < 8; ++j)
        r[j] = bfs(__bfloat162float(__builtin_bit_cast(bf16, v[j])) * rs * ci[j]);
    *(s8*)&y2x[i] = r;
}

// ---------------- flash10: flash8's proven inner pipeline (Ps-LDS transpose, 2 barriers/tile)
// on a 512-block grid: one 64-row q-tile per 4-wave block, pair-balanced jt so linear-id
// pairs (i, i+256) — same CU under round-robin dispatch — sum to 17 s-tile units.
// 60.9 KB LDS -> 2 blocks/CU co-resident with independent barriers; no dead waves. ----------------
__global__ __launch_bounds__(256) void flash10_kernel(
    const bf16* __restrict__ x2y, const bf16* __restrict__ y2x,
    const bf16* __restrict__ vTx, const bf16* __restrict__ vTy,
    const bf16* __restrict__ qkv_x, const float* __restrict__ x,
    bf16* __restrict__ cval_bf, bf16* __restrict__ sval_bf)
{
    __shared__ short Kc[64][264];
    __shared__ short Ksf[64][72];
    __shared__ short Vb[64][72];
    __shared__ short Ps[4][16][68];
    const int tid = threadIdx.x;
    const int wave = tid >> 6, lane = tid & 63;
    const int quad = lane >> 4, l16 = lane & 15;
    const int bh = blockIdx.x, b = bh >> 3, h = bh & 7;
    const int jt = (blockIdx.y < 8) ? (15 - (int)blockIdx.y) : ((int)blockIdx.y - 8);
    const int rb = jt * 64 + wave * 16;
    const int nst = jt + 1;

    s8 qc[8], qs[2];
    {
        const bf16* qp = x2y + (size_t)(bh * T_ + rb + l16) * M_ + quad * 8;
        #pragma unroll
        for (int f = 0; f < 8; ++f) qc[f] = *(const s8*)(qp + f * 32);
        const bf16* qsp = qkv_x + (size_t)(b * T_ + rb + l16) * C3_ + h * HD_ + quad * 8;
        qs[0] = *(const s8*)qsp;
        qs[1] = *(const s8*)(qsp + 32);
    }

    // cross-attention dense part: x2y @ vTy
    f4 ocv[4];
    #pragma unroll
    for (int dt = 0; dt < 4; ++dt) ocv[dt] = (f4)0.f;
    {
        const bf16* vb = vTy + (size_t)(bh * 64 + l16) * M_ + quad * 8;
        #pragma unroll
        for (int f = 0; f < 8; ++f)
            #pragma unroll
            for (int dt = 0; dt < 4; ++dt) {
                s8 bv = *(const s8*)(vb + (size_t)dt * 16 * M_ + f * 32);
                ocv[dt] = MFMA16(qc[f], bv, ocv[dt]);
            }
    }

    f4 oc[4], os_[4];
    float lc[4] = {0.f, 0.f, 0.f, 0.f}, ls_[4] = {0.f, 0.f, 0.f, 0.f};
    #pragma unroll
    for (int dt = 0; dt < 4; ++dt) { oc[dt] = (f4)0.f; os_[dt] = (f4)0.f; }

    // stage s-tile 0
    #pragma unroll
    for (int tl = 0; tl < 8; ++tl) {
        int g = tid + tl * 256, row = g >> 5, grp = g & 31;
        *(s8*)&Kc[row][grp * 8] = *(const s8*)&y2x[(size_t)(bh * T_ + row) * M_ + grp * 8];
    }
    #pragma unroll
    for (int tl = 0; tl < 2; ++tl) {
        int g = tid + tl * 256, row = g >> 3, grp = g & 7;
        *(s8*)&Ksf[row][grp * 8] =
            *(const s8*)&qkv_x[(size_t)(b * T_ + row) * C3_ + C_ + h * HD_ + grp * 8];
        *(s8*)&Vb[row][grp * 8] = *(const s8*)&vTx[(size_t)(bh * 64 + row) * T_ + grp * 8];
    }
    __syncthreads();

    for (int st = 0; st < nst; ++st) {
        const int s0 = st * 64;
        const bool pf = (st + 1) < nst;
        s8 kcp[8], ksp[2], vp[2];
        if (pf) {
            const int sn = s0 + 64;
            #pragma unroll
            for (int tl = 0; tl < 8; ++tl) {
                int g = tid + tl * 256, row = g >> 5, grp = g & 31;
                kcp[tl] = *(const s8*)&y2x[(size_t)(bh * T_ + sn + row) * M_ + grp * 8];
            }
            #pragma unroll
            for (int tl = 0; tl < 2; ++tl) {
                int g = tid + tl * 256, row = g >> 3, grp = g & 7;
                ksp[tl] = *(const s8*)&qkv_x[(size_t)(b * T_ + sn + row) * C3_ + C_ + h * HD_ + grp * 8];
                vp[tl] = *(const s8*)&vTx[(size_t)(bh * 64 + row) * T_ + sn + grp * 8];
            }
        }
        {
            // chain QK
            f4 sc[4];
            #pragma unroll
            for (int nt = 0; nt < 4; ++nt) sc[nt] = (f4)0.f;
            #pragma unroll
            for (int f = 0; f < 8; ++f)
                #pragma unroll
                for (int nt = 0; nt < 4; ++nt) {
                    s8 bv = *(const s8*)&Kc[nt * 16 + l16][f * 32 + quad * 8];
                    sc[nt] = MFMA16(qc[f], bv, sc[nt]);
                }
            // self QK
            f4 ss[4];
            #pragma unroll
            for (int nt = 0; nt < 4; ++nt) ss[nt] = (f4)0.f;
            #pragma unroll
            for (int f = 0; f < 2; ++f)
                #pragma unroll
                for (int nt = 0; nt < 4; ++nt) {
                    s8 bv = *(const s8*)&Ksf[nt * 16 + l16][f * 32 + quad * 8];
                    ss[nt] = MFMA16(qs[f], bv, ss[nt]);
                }
            // chain exp + Ps transpose + PV
            #pragma unroll
            for (int reg = 0; reg < 4; ++reg) {
                const int t_g = rb + quad * 4 + reg;
                #pragma unroll
                for (int nt = 0; nt < 4; ++nt) {
                    float pv = (s0 + nt * 16 + l16 <= t_g) ? __expf(sc[nt][reg] * (1.f / 16.f)) : 0.f;
                    lc[reg] += pv;
                    Ps[wave][quad * 4 + reg][nt * 16 + l16] = bfs(pv);
                }
            }
            #pragma unroll
            for (int ks = 0; ks < 2; ++ks) {
                const short* pp = &Ps[wave][l16][ks * 32 + quad * 8];
                s4 alo = *(const s4*)pp;
                s4 ahi = *(const s4*)(pp + 4);
                s8 a;
                a[0] = alo[0]; a[1] = alo[1]; a[2] = alo[2]; a[3] = alo[3];
                a[4] = ahi[0]; a[5] = ahi[1]; a[6] = ahi[2]; a[7] = ahi[3];
                #pragma unroll
                for (int dt = 0; dt < 4; ++dt) {
                    s8 bv = *(const s8*)&Vb[dt * 16 + l16][ks * 32 + quad * 8];
                    oc[dt] = MFMA16(a, bv, oc[dt]);
                }
            }
            // self exp + Ps transpose + PV
            #pragma unroll
            for (int reg = 0; reg < 4; ++reg) {
                const int t_g = rb + quad * 4 + reg;
                #pragma unroll
                for (int nt = 0; nt < 4; ++nt) {
                    float pv = (s0 + nt * 16 + l16 <= t_g) ? __expf(ss[nt][reg] * 0.125f) : 0.f;
                    ls_[reg] += pv;
                    Ps[wave][quad * 4 + reg][nt * 16 + l16] = bfs(pv);
                }
            }
            #pragma unroll
            for (int ks = 0; ks < 2; ++ks) {
                const short* pp = &Ps[wave][l16][ks * 32 + quad * 8];
                s4 alo = *(const s4*)pp;
                s4 ahi = *(const s4*)(pp + 4);
                s8 a;
                a[0] = alo[0]; a[1] = alo[1]; a[2] = alo[2]; a[3] = alo[3];
                a[4] = ahi[0]; a[5] = ahi[1]; a[6] = ahi[2]; a[7] = ahi[3];
                #pragma unroll
                for (int dt = 0; dt < 4; ++dt) {
                    s8 bv = *(const s8*)&Vb[dt * 16 + l16][ks * 32 + quad * 8];
                    os_[dt] = MFMA16(a, bv, os_[dt]);
                }
            }
        }
        __syncthreads();   // all waves done reading Kc/Ksf/Vb
        if (pf) {
            #pragma unroll
            for (int tl = 0; tl < 8; ++tl) {
                int g = tid + tl * 256, row = g >> 5, grp = g & 31;
                *(s8*)&Kc[row][grp * 8] = kcp[tl];
            }
            #pragma unroll
            for (int tl = 0; tl < 2; ++tl) {
                int g = tid + tl * 256, row = g >> 3, grp = g & 7;
                *(s8*)&Ksf[row][grp * 8] = ksp[tl];
                *(s8*)&Vb[row][grp * 8] = vp[tl];
            }
        }
        __syncthreads();   // new tile visible
    }

    #pragma unroll
    for (int reg = 0; reg < 4; ++reg) {
        float l1 = lc[reg], l2 = ls_[reg];
        l1 += __shfl_xor(l1, 1); l1 += __shfl_xor(l1, 2);
        l1 += __shfl_xor(l1, 4); l1 += __shfl_xor(l1, 8);
        l2 += __shfl_xor(l2, 1); l2 += __shfl_xor(l2, 2);
        l2 += __shfl_xor(l2, 4); l2 += __shfl_xor(l2, 8);
        const float i1 = 1.f / l1, i2 = 1.f / l2;
        const int t = rb + quad * 4 + reg;
        #pragma unroll
        for (int dt = 0; dt < 4; ++dt) {
            size_t idx = (size_t)(b * T_ + t) * C_ + h * HD_ + dt * 16 + l16;
            float cv = ocv[dt][reg] + oc[dt][reg] * i1 + x[idx];
            cval_bf[idx] = __float2bfloat16(cv);
            float sv = os_[dt][reg] * i2;
            sval_bf[idx] = __float2bfloat16(sv);
        }
    }
}

// ---------------- fused dual gate GEMM + sigmoid + combine -> gated bf16 ----------------
__global__ __launch_bounds__(256) void gatefuse_kernel(
    const bf16* __restrict__ svalb, const bf16* __restrict__ cvalb,
    const bf16* __restrict__ WTgs, const bf16* __restrict__ WTgc,
    const float* __restrict__ bgs, const float* __restrict__ bgc,
    bf16* __restrict__ gated)
{
    __shared__ short Sb[128][72], Cb[128][72], W1b[64][72], W2b[64][72];
    const int tid = threadIdx.x;
    const int wave = tid >> 6, lane = tid & 63;
    const int quad = lane >> 4, l16 = lane & 15;
    const int n0 = blockIdx.y * 64, m0 = blockIdx.x * 128;
    f4 aS[2][4], aC[2][4];
    #pragma unroll
    for (int mt = 0; mt < 2; ++mt)
        #pragma unroll
        for (int nt = 0; nt < 4; ++nt) { aS[mt][nt] = (f4)0.f; aC[mt][nt] = (f4)0.f; }

    for (int k0 = 0; k0 < C_; k0 += 64) {
        #pragma unroll
        for (int tl = 0; tl < 4; ++tl) {
            int g = tid + tl * 256, row = g >> 3, grp = g & 7;
            *(s8*)&Sb[row][grp * 8] = *(const s8*)&svalb[(size_t)(m0 + row) * C_ + k0 + grp * 8];
            *(s8*)&Cb[row][grp * 8] = *(const s8*)&cvalb[(size_t)(m0 + row) * C_ + k0 + grp * 8];
        }
        #pragma unroll
        for (int tl = 0; tl < 2; ++tl) {
            int g = tid + tl * 256, n = g >> 3, grp = g & 7;
            *(s8*)&W1b[n][grp * 8] = *(const s8*)&WTgs[(size_t)(n0 + n) * C_ + k0 + grp * 8];
            *(s8*)&W2b[n][grp * 8] = *(const s8*)&WTgc[(size_t)(n0 + n) * C_ + k0 + grp * 8];
        }
        __syncthreads();
        #pragma unroll
        for (int ks = 0; ks < 2; ++ks) {
            s8 s0f = *(const s8*)&Sb[wave * 32 + l16][ks * 32 + quad * 8];
            s8 s1f = *(const s8*)&Sb[wave * 32 + 16 + l16][ks * 32 + quad * 8];
            s8 c0f = *(const s8*)&Cb[wave * 32 + l16][ks * 32 + quad * 8];
            s8 c1f = *(const s8*)&Cb[wave * 32 + 16 + l16][ks * 32 + quad * 8];
            #pragma unroll
            for (int nt = 0; nt < 4; ++nt) {
                s8 w1 = *(const s8*)&W1b[nt * 16 + l16][ks * 32 + quad * 8];
                s8 w2 = *(const s8*)&W2b[nt * 16 + l16][ks * 32 + quad * 8];
                aS[0][nt] = MFMA16(s0f, w1, aS[0][nt]);
                aS[1][nt] = MFMA16(s1f, w1, aS[1][nt]);
                aC[0][nt] = MFMA16(c0f, w2, aC[0][nt]);
                aC[1][nt] = MFMA16(c1f, w2, aC[1][nt]);
            }
        }
        __syncthreads();
    }
    #pragma unroll
    for (int mt = 0; mt < 2; ++mt)
        #pragma unroll
        for (int nt = 0; nt < 4; ++nt) {
            int col = n0 + nt * 16 + l16;
            float b1 = bgs[col], b2 = bgc[col];
            #pragma unroll
            for (int reg = 0; reg < 4; ++reg) {
                int row = m0 + wave * 32 + mt * 16 + quad * 4 + reg;
                size_t idx = (size_t)row * C_ + col;
                float gs = 1.f / (1.f + __expf(-(aS[mt][nt][reg] + b1)));
                float gc = 1.f / (1.f + __expf(-(aC[mt][nt][reg] + b2)));
                float cvv = __bfloat162float(cvalb[idx]);
                float svv = __bfloat162float(svalb[idx]);
                gated[idx] = __float2bfloat16(gs * cvv + gc * svv);
            }
        }
}

extern "C" void kernel_launch(void* const* d_in, const int* in_sizes, int n_in,
                              void* d_out, int out_size, void* d_ws, size_t ws_size,
                              hipStream_t stream)
{
    const float* x      = (const float*)d_in[0];
    const float* y      = (const float*)d_in[1];
    // d_in[2]: attn_x_mask — structurally causal tril, computed inline
    const float* Wqkv_x = (const float*)d_in[3];
    const float* bqkv_x = (const float*)d_in[4];
    const float* Wqkv_y = (const float*)d_in[5];
    const float* bqkv_y = (const float*)d_in[6];
    const float* w4x    = (const float*)d_in[7];
    const float* w4y    = (const float*)d_in[8];
    const float* w4xy   = (const float*)d_in[9];
    const float* Wgs    = (const float*)d_in[10];
    const float* bgs    = (const float*)d_in[11];
    const float* Wgc    = (const float*)d_in[12];
    const float* bgc    = (const float*)d_in[13];
    const float* Wp     = (const float*)d_in[14];
    const float* bp     = (const float*)d_in[15];

    // Workspace (f-word offsets; proven layout)
    float* ws = (float*)d_ws;
    bf16*  qkv_x_bf = (bf16*)(ws + 0);           // 6,291,456 bf16
    bf16*  qkv_y_bf = (bf16*)(ws + 3145728);     // 1,572,864 bf16
    bf16*  gated_bf = (bf16*)(ws + 3932160);
    bf16*  cval_bf  = (bf16*)(ws + 5242880);
    bf16*  x2y_bf   = (bf16*)(ws + 12320768);    // 8,388,608 bf16 (written by catt3r)
    bf16*  x_bf     = x2y_bf;                    //   pre-QKV reuse
    bf16*  y_bf     = (bf16*)(ws + 13369344);    //   pre-QKV reuse
    bf16*  y2x_bf   = (bf16*)(ws + 16515072);    // 8,388,608 bf16 (written by y2xw)
    bf16*  vTx_bf   = (bf16*)(ws + 20709376);    // 2,097,152 bf16
    bf16*  vTy_bf   = (bf16*)(ws + 21757952);    // 524,288 bf16
    float* psum_    = ws + 22020096;             // 131,072 f
    bf16*  qw_bf    = (bf16*)(ws + 26214400);    // 2,097,152 bf16 (dead after catt3r)
    bf16*  sval_bf  = qw_bf;                     //   reuse
    bf16*  WT_x     = (bf16*)(ws + 27262976);    // 786,432 bf16
    bf16*  WT_y     = (bf16*)(ws + 27656192);
    bf16*  WT_gs    = (bf16*)(ws + 28049408);    // 262,144 bf16
    bf16*  WT_gc    = (bf16*)(ws + 28180480);
    bf16*  WT_p    = (bf16*)(ws + 28311552);
    float* catt1b   = ws + 28442624;             // 32,768 f
    float* catt2b   = ws + 28475392;             //  8,192 f
    float* colinv   = ws + 28483584;             //  8,192 f
    float* rowsum_  = ws + 28491776;             // 32,768 f

    // 0: one prep dispatch
    prep_kernel<<<1856, 256, 0, stream>>>(
        Wqkv_x, Wqkv_y, Wgs, Wgc, Wp, x, y,
        WT_x, WT_y, WT_gs, WT_gc, WT_p, x_bf, y_bf);

    // 1-2: QKV projections
    gemm_staged_kernel<bf16><<<dim3(32, 24), 256, 0, stream>>>(x_bf, WT_x, bqkv_x, qkv_x_bf, C3_, C_);
    gemm_staged_kernel<bf16><<<dim3(8, 24), 256, 0, stream>>>(y_bf, WT_y, bqkv_y, qkv_y_bf, C3_, C_);

    // 3: catt1/catt2/qw
    qwcatt_kernel<<<1184, 256, 0, stream>>>(
        qkv_x_bf, qkv_y_bf, w4x, w4y, w4xy, catt1b, catt2b, qw_bf);

    // 4: fused logits + row softmax -> x2y + rowsum + col partials
    catt3r_kernel<<<dim3(32, 16), 256, 0, stream>>>(
        qw_bf, qkv_y_bf, catt1b, catt2b, x2y_bf, rowsum_, psum_);

    // 5: colfin + V transposes
    colfin_vtrans_kernel<<<672, 256, 0, stream>>>(psum_, colinv, qkv_x_bf, qkv_y_bf, vTx_bf, vTy_bf);

    // 6: y2x = x2y * rowsum * colinv
    y2xw_kernel<<<4096, 256, 0, stream>>>(x2y_bf, rowsum_, colinv, y2x_bf);

    // 7: 512-block pair-balanced flash, flash8 inner pipeline
    flash10_kernel<<<dim3(32, 16), 256, 0, stream>>>(
        x2y_bf, y2x_bf, vTx_bf, vTy_bf, qkv_x_bf, x, cval_bf, sval_bf);

    // 8: fused gates (bf16 elementwise)
    gatefuse_kernel<<<dim3(32, 8), 256, 0, stream>>>(
        sval_bf, cval_bf, WT_gs, WT_gc, bgs, bgc, gated_bf);

    // 9: out = gated @ Wp + bp
    gemm_staged_kernel<float><<<dim3(32, 8), 256, 0, stream>>>(
        gated_bf, WT_p, bp, (float*)d_out, C_, C_);
}

// Round 4
// 229.144 us; speedup vs baseline: 1.0499x; 1.0499x over previous
//
#include <hip/hip_runtime.h>
#include <hip/hip_bf16.h>

typedef __hip_bfloat16 bf16;
using f4 = __attribute__((ext_vector_type(4))) float;
using s8 = __attribute__((ext_vector_type(8))) short;
using s4 = __attribute__((ext_vector_type(4))) short;

__device__ __forceinline__ void storeOut(float* p, float v) { *p = v; }
__device__ __forceinline__ void storeOut(bf16* p, float v) { *p = __float2bfloat16(v); }
__device__ __forceinline__ short bfs(float x) { return __builtin_bit_cast(short, __float2bfloat16(x)); }

constexpr int B_ = 4, T_ = 1024, M_ = 256, C_ = 512, H_ = 8, HD_ = 64, C3_ = 1536;

#define MFMA16(a, b, c) __builtin_amdgcn_mfma_f32_16x16x32_bf16((a), (b), (c), 0, 0, 0)

// ---------------- prep: 5 weight transposes (fp32 KxN -> bf16 NxK) + 2 converts ----------------
__global__ __launch_bounds__(256) void prep_kernel(
    const float* __restrict__ Wqkv_x, const float* __restrict__ Wqkv_y,
    const float* __restrict__ Wgs, const float* __restrict__ Wgc, const float* __restrict__ Wp,
    const float* __restrict__ x, const float* __restrict__ y,
    bf16* __restrict__ WT_x, bf16* __restrict__ WT_y, bf16* __restrict__ WT_gs,
    bf16* __restrict__ WT_gc, bf16* __restrict__ WT_p,
    bf16* __restrict__ x_bf, bf16* __restrict__ y_bf)
{
    __shared__ float Ls[64][65];
    const int tid = threadIdx.x;
    const int bid = blockIdx.x;
    if (bid < 576) {
        const float* W; bf16* WT; int N, t;
        if (bid < 192)      { W = Wqkv_x; WT = WT_x;  N = C3_; t = bid; }
        else if (bid < 384) { W = Wqkv_y; WT = WT_y;  N = C3_; t = bid - 192; }
        else if (bid < 448) { W = Wgs;    WT = WT_gs; N = C_;  t = bid - 384; }
        else if (bid < 512) { W = Wgc;    WT = WT_gc; N = C_;  t = bid - 448; }
        else                { W = Wp;     WT = WT_p;  N = C_;  t = bid - 512; }
        const int K = C_;
        const int tw = N >> 6;
        const int n0 = (t % tw) * 64, k0 = (t / tw) * 64;
        for (int i = tid; i < 1024; i += 256) {
            int kr = i >> 4, ng = i & 15;
            float4 v = *(const float4*)&W[(size_t)(k0 + kr) * N + n0 + ng * 4];
            Ls[ng * 4 + 0][kr] = v.x; Ls[ng * 4 + 1][kr] = v.y;
            Ls[ng * 4 + 2][kr] = v.z; Ls[ng * 4 + 3][kr] = v.w;
        }
        __syncthreads();
        for (int i = tid; i < 512; i += 256) {
            int n = i >> 3, kg = i & 7;
            s8 r;
            #pragma unroll
            for (int j = 0; j < 8; ++j) r[j] = bfs(Ls[n][kg * 8 + j]);
            *(s8*)&WT[(size_t)(n0 + n) * K + k0 + kg * 8] = r;
        }
    } else if (bid < 1600) {
        int i = (bid - 576) * 2048 + tid * 8;
        s8 r;
        #pragma unroll
        for (int j = 0; j < 8; ++j) r[j] = bfs(x[i + j]);
        *(s8*)&x_bf[i] = r;
    } else {
        int i = (bid - 1600) * 2048 + tid * 8;
        s8 r;
        #pragma unroll
        for (int j = 0; j < 8; ++j) r[j] = bfs(y[i + j]);
        *(s8*)&y_bf[i] = r;
    }
}

// ---------------- merged catt1/catt2 + qw (one dispatch) ----------------
__global__ __launch_bounds__(256) void qwcatt_kernel(
    const bf16* __restrict__ qkv_x, const bf16* __restrict__ qkv_y,
    const float* __restrict__ w4x, const float* __restrict__ w4y,
    const float* __restrict__ w4xy,
    float* __restrict__ catt1b, float* __restrict__ catt2b, bf16* __restrict__ qw)
{
    const int bid = blockIdx.x;
    const int tid = threadIdx.x;
    if (bid < 160) {
        int i = bid * 256 + tid;   // 0..40959
        const bf16* row; const float* w; float* out; int oi;
        if (i < 32768) {
            int bh = i >> 10, t = i & 1023, b = bh >> 3, h = bh & 7;
            row = qkv_x + (size_t)(b * T_ + t) * C3_ + h * HD_;
            w = w4x + h * HD_; out = catt1b; oi = i;
        } else {
            int j = i - 32768;
            int bh = j >> 8, m = j & 255, b = bh >> 3, h = bh & 7;
            row = qkv_y + (size_t)(b * M_ + m) * C3_ + h * HD_;
            w = w4y + h * HD_; out = catt2b; oi = j;
        }
        float s = 0.f;
        #pragma unroll
        for (int d = 0; d < HD_; ++d) s = fmaf(__bfloat162float(row[d]), w[d], s);
        out[oi] = s;
    } else {
        int o = ((bid - 160) * 256 + tid) * 8;
        int row = o >> 9, c = o & 511;
        const bf16* src = qkv_x + (size_t)row * C3_ + c;
        s8 r;
        #pragma unroll
        for (int j = 0; j < 8; ++j) r[j] = bfs(__bfloat162float(src[j]) * w4xy[c + j]);
        *(s8*)&qw[o] = r;
    }
}

// ---------------- LDS-staged MFMA GEMM (m-major grid) ----------------
template <typename OT>
__global__ __launch_bounds__(256) void gemm_staged_kernel(
    const bf16* __restrict__ A, const bf16* __restrict__ WT, const float* __restrict__ bias,
    OT* __restrict__ Cmat, int N, int K)
{
    __shared__ short Asb[128][72];
    __shared__ short Bsb[64][72];
    const int tid = threadIdx.x;
    const int wave = tid >> 6, lane = tid & 63;
    const int quad = lane >> 4, l16 = lane & 15;
    const int n0 = blockIdx.y * 64, m0 = blockIdx.x * 128;
    f4 acc[2][4];
    #pragma unroll
    for (int mt = 0; mt < 2; ++mt)
        #pragma unroll
        for (int nt = 0; nt < 4; ++nt) acc[mt][nt] = (f4)0.f;

    for (int k0 = 0; k0 < K; k0 += 64) {
        #pragma unroll
        for (int tl = 0; tl < 4; ++tl) {
            int g = tid + tl * 256, row = g >> 3, grp = g & 7;
            *(s8*)&Asb[row][grp * 8] = *(const s8*)&A[(size_t)(m0 + row) * K + k0 + grp * 8];
        }
        #pragma unroll
        for (int tl = 0; tl < 2; ++tl) {
            int g = tid + tl * 256, n = g >> 3, grp = g & 7;
            *(s8*)&Bsb[n][grp * 8] = *(const s8*)&WT[(size_t)(n0 + n) * K + k0 + grp * 8];
        }
        __syncthreads();
        #pragma unroll
        for (int ks = 0; ks < 2; ++ks) {
            s8 a0 = *(const s8*)&Asb[wave * 32 + l16][ks * 32 + quad * 8];
            s8 a1 = *(const s8*)&Asb[wave * 32 + 16 + l16][ks * 32 + quad * 8];
            #pragma unroll
            for (int nt = 0; nt < 4; ++nt) {
                s8 bv = *(const s8*)&Bsb[nt * 16 + l16][ks * 32 + quad * 8];
                acc[0][nt] = MFMA16(a0, bv, acc[0][nt]);
                acc[1][nt] = MFMA16(a1, bv, acc[1][nt]);
            }
        }
        __syncthreads();
    }
    #pragma unroll
    for (int mt = 0; mt < 2; ++mt)
        #pragma unroll
        for (int nt = 0; nt < 4; ++nt) {
            int col = n0 + nt * 16 + l16;
            float bb = bias[col];
            #pragma unroll
            for (int reg = 0; reg < 4; ++reg) {
                int row = m0 + wave * 32 + mt * 16 + quad * 4 + reg;
                storeOut(&Cmat[(size_t)row * N + col], acc[mt][nt][reg] + bb);
            }
        }
}

// ---------------- catt3r: logits + row softmax -> x2y bf16 + rowsum + col partial sums ----------------
__global__ __launch_bounds__(256) void catt3r_kernel(
    const bf16* __restrict__ qw, const bf16* __restrict__ qkv_y,
    const float* __restrict__ catt1, const float* __restrict__ catt2,
    bf16* __restrict__ x2y, float* __restrict__ rowsum_, float* __restrict__ psum)
{
    __shared__ float redc[4][256];
    const int tid = threadIdx.x;
    const int wave = tid >> 6, lane = tid & 63;
    const int quad = lane >> 4, l16 = lane & 15;
    const int bh = blockIdx.x, b = bh >> 3, h = bh & 7;
    const int t0 = blockIdx.y * 64;
    f4 sc[4][4];
    #pragma unroll
    for (int mt = 0; mt < 4; ++mt)
        #pragma unroll
        for (int nt = 0; nt < 4; ++nt) sc[mt][nt] = (f4)0.f;

    const bf16* ap = qw + (size_t)(b * T_ + t0 + wave * 16 + l16) * C_ + h * HD_ + quad * 8;
    s8 a0 = *(const s8*)ap;
    s8 a1 = *(const s8*)(ap + 32);
    const bf16* bp = qkv_y + (size_t)(b * M_ + l16) * C3_ + C_ + h * HD_ + quad * 8;
    #pragma unroll
    for (int mt = 0; mt < 4; ++mt)
        #pragma unroll
        for (int nt = 0; nt < 4; ++nt) {
            const bf16* bq = bp + (size_t)(mt * 64 + nt * 16) * C3_;
            sc[mt][nt] = MFMA16(a0, *(const s8*)bq, sc[mt][nt]);
            sc[mt][nt] = MFMA16(a1, *(const s8*)(bq + 32), sc[mt][nt]);
        }

    float c1[4];
    #pragma unroll
    for (int reg = 0; reg < 4; ++reg)
        c1[reg] = catt1[bh * T_ + t0 + wave * 16 + quad * 4 + reg];
    #pragma unroll
    for (int mt = 0; mt < 4; ++mt)
        #pragma unroll
        for (int nt = 0; nt < 4; ++nt) {
            float c2 = catt2[bh * M_ + mt * 64 + nt * 16 + l16];
            #pragma unroll
            for (int reg = 0; reg < 4; ++reg)
                sc[mt][nt][reg] = __expf(sc[mt][nt][reg] * 0.125f + c1[reg] + c2);
        }

    #pragma unroll
    for (int reg = 0; reg < 4; ++reg) {
        float rs = 0.f;
        #pragma unroll
        for (int mt = 0; mt < 4; ++mt)
            #pragma unroll
            for (int nt = 0; nt < 4; ++nt) rs += sc[mt][nt][reg];
        rs += __shfl_xor(rs, 1); rs += __shfl_xor(rs, 2);
        rs += __shfl_xor(rs, 4); rs += __shfl_xor(rs, 8);
        const int t = t0 + wave * 16 + quad * 4 + reg;
        if (l16 == 0) rowsum_[bh * T_ + t] = rs;
        const float ri = 1.f / rs;
        #pragma unroll
        for (int mt = 0; mt < 4; ++mt)
            #pragma unroll
            for (int nt = 0; nt < 4; ++nt)
                x2y[((size_t)bh * T_ + t) * M_ + mt * 64 + nt * 16 + l16] =
                    __float2bfloat16(sc[mt][nt][reg] * ri);
    }

    #pragma unroll
    for (int mt = 0; mt < 4; ++mt)
        #pragma unroll
        for (int nt = 0; nt < 4; ++nt) {
            float es = sc[mt][nt][0] + sc[mt][nt][1] + sc[mt][nt][2] + sc[mt][nt][3];
            es += __shfl_xor(es, 16);
            es += __shfl_xor(es, 32);
            if (quad == 0) redc[wave][mt * 64 + nt * 16 + l16] = es;
        }
    __syncthreads();
    psum[((size_t)bh * 16 + blockIdx.y) * M_ + tid] =
        redc[0][tid] + redc[1][tid] + redc[2][tid] + redc[3][tid];
}

// ---------------- merged colfin + V transposes (one dispatch) ----------------
__global__ __launch_bounds__(256) void colfin_vtrans_kernel(
    const float* __restrict__ psum, float* __restrict__ colinv,
    const bf16* __restrict__ qkv_x, const bf16* __restrict__ qkv_y,
    bf16* __restrict__ vTx, bf16* __restrict__ vTy)
{
    __shared__ short Ls[64][68];
    const int tid = threadIdx.x;
    int bid = blockIdx.x;
    if (bid < 32) {
        const int bh = bid, m = tid;
        float s = 0.f;
        #pragma unroll
        for (int ch = 0; ch < 16; ++ch) s += psum[(bh * 16 + ch) * M_ + m];
        colinv[bh * M_ + m] = 1.f / s;
        return;
    }
    bid -= 32;
    const bf16* qkv; bf16* vT; int Nrows, bh, t0;
    if (bid < 512) { qkv = qkv_x; vT = vTx; Nrows = T_; bh = bid >> 4; t0 = (bid & 15) * 64; }
    else { bid -= 512; qkv = qkv_y; vT = vTy; Nrows = M_; bh = bid >> 2; t0 = (bid & 3) * 64; }
    const int b = bh >> 3, h = bh & 7;
    for (int i = tid; i < 4096; i += 256) {
        int tl = i >> 6, d = i & 63;
        Ls[d][tl] = __builtin_bit_cast(short,
            qkv[(size_t)(b * Nrows + t0 + tl) * C3_ + 2 * C_ + h * HD_ + d]);
    }
    __syncthreads();
    for (int i = tid; i < 4096; i += 256) {
        int d = i >> 6, tl = i & 63;
        vT[((size_t)bh * 64 + d) * Nrows + t0 + tl] = __builtin_bit_cast(bf16, Ls[d][tl]);
    }
}

// ---------------- y2xw: y2x = x2y * rowsum * colinv ----------------
__global__ __launch_bounds__(256) void y2xw_kernel(
    const bf16* __restrict__ x2y, const float* __restrict__ rowsum_,
    const float* __restrict__ colinv, bf16* __restrict__ y2x)
{
    const int i = (blockIdx.x * 256 + threadIdx.x) * 8;
    const int row = i >> 8, m = i & 255, bh = row >> 10;
    const float rs = rowsum_[row];
    s8 v = *(const s8*)&x2y[i];
    const float4 c0 = *(const float4*)&colinv[bh * M_ + m];
    const float4 c4 = *(const float4*)&colinv[bh * M_ + m + 4];
    float ci[8] = {c0.x, c0.y, c0.z, c0.w, c4.x, c4.y, c4.z, c4.w};
    s8 r;
    #pragma unroll
    for (int j = 0; j < 8; ++j)
        r[j] = bfs(__bfloat162float(__builtin_bit_cast(bf16, v[j])) * rs * ci[j]);
    *(s8*)&y2x[i] = r;
}

// ---------------- flash11 (barrier-uniform): flash8 shell + split-assist balance.
// Group A (waves 0-3): q1 tiles 0..p, then q2 tiles 0..7-p (partials).
// Group B (waves 4-7): q2 tiles 8-p..15-p. 9 uniform phases; every barrier site is
// textually unconditional and executed by all threads (no divergent barriers).
// Dual buffer sets; A's partials merged into B after the loop. ----------------
__device__ __forceinline__ void attn_unit(
    const short* __restrict__ Kc, const short* __restrict__ Ksf, const short* __restrict__ Vb,
    short* __restrict__ PsW, const s8 qc[8], const s8 qs[2],
    f4 (&oc)[4], f4 (&os)[4], float (&lc)[4], float (&ls)[4],
    int s0, bool diag, int trow, int quad, int l16)
{
    // chain QK (k = M = 256)
    f4 sc[4];
    #pragma unroll
    for (int nt = 0; nt < 4; ++nt) sc[nt] = (f4)0.f;
    #pragma unroll
    for (int f = 0; f < 8; ++f)
        #pragma unroll
        for (int nt = 0; nt < 4; ++nt) {
            s8 bv = *(const s8*)&Kc[(nt * 16 + l16) * 264 + f * 32 + quad * 8];
            sc[nt] = MFMA16(qc[f], bv, sc[nt]);
        }
    // self QK (k = HD = 64)
    f4 ss[4];
    #pragma unroll
    for (int nt = 0; nt < 4; ++nt) ss[nt] = (f4)0.f;
    #pragma unroll
    for (int f = 0; f < 2; ++f)
        #pragma unroll
        for (int nt = 0; nt < 4; ++nt) {
            s8 bv = *(const s8*)&Ksf[(nt * 16 + l16) * 72 + f * 32 + quad * 8];
            ss[nt] = MFMA16(qs[f], bv, ss[nt]);
        }
    // chain exp + Ps transpose + PV
    #pragma unroll
    for (int reg = 0; reg < 4; ++reg) {
        const int t_g = trow + quad * 4 + reg;
        #pragma unroll
        for (int nt = 0; nt < 4; ++nt) {
            float pv = __expf(sc[nt][reg] * 0.0625f);
            if (diag && (s0 + nt * 16 + l16 > t_g)) pv = 0.f;
            lc[reg] += pv;
            PsW[(quad * 4 + reg) * 68 + nt * 16 + l16] = bfs(pv);
        }
    }
    #pragma unroll
    for (int ks = 0; ks < 2; ++ks) {
        const short* pp = &PsW[l16 * 68 + ks * 32 + quad * 8];
        s4 alo = *(const s4*)pp;
        s4 ahi = *(const s4*)(pp + 4);
        s8 a;
        a[0] = alo[0]; a[1] = alo[1]; a[2] = alo[2]; a[3] = alo[3];
        a[4] = ahi[0]; a[5] = ahi[1]; a[6] = ahi[2]; a[7] = ahi[3];
        #pragma unroll
        for (int dt = 0; dt < 4; ++dt) {
            s8 bv = *(const s8*)&Vb[(dt * 16 + l16) * 72 + ks * 32 + quad * 8];
            oc[dt] = MFMA16(a, bv, oc[dt]);
        }
    }
    // self exp + Ps transpose + PV
    #pragma unroll
    for (int reg = 0; reg < 4; ++reg) {
        const int t_g = trow + quad * 4 + reg;
        #pragma unroll
        for (int nt = 0; nt < 4; ++nt) {
            float pv = __expf(ss[nt][reg] * 0.125f);
            if (diag && (s0 + nt * 16 + l16 > t_g)) pv = 0.f;
            ls[reg] += pv;
            PsW[(quad * 4 + reg) * 68 + nt * 16 + l16] = bfs(pv);
        }
    }
    #pragma unroll
    for (int ks = 0; ks < 2; ++ks) {
        const short* pp = &PsW[l16 * 68 + ks * 32 + quad * 8];
        s4 alo = *(const s4*)pp;
        s4 ahi = *(const s4*)(pp + 4);
        s8 a;
        a[0] = alo[0]; a[1] = alo[1]; a[2] = alo[2]; a[3] = alo[3];
        a[4] = ahi[0]; a[5] = ahi[1]; a[6] = ahi[2]; a[7] = ahi[3];
        #pragma unroll
        for (int dt = 0; dt < 4; ++dt) {
            s8 bv = *(const s8*)&Vb[(dt * 16 + l16) * 72 + ks * 32 + quad * 8];
            os[dt] = MFMA16(a, bv, os[dt]);
        }
    }
}

__global__ __launch_bounds__(512, 2) void flash11_kernel(
    const bf16* __restrict__ x2y, const bf16* __restrict__ y2x,
    const bf16* __restrict__ vTx, const bf16* __restrict__ vTy,
    const bf16* __restrict__ qkv_x, const float* __restrict__ x,
    bf16* __restrict__ cval_bf, bf16* __restrict__ sval_bf)
{
    __shared__ short KcA[64][264], KcB[64][264];
    __shared__ short KsfA[64][72], KsfB[64][72];
    __shared__ short VbA[64][72], VbB[64][72];
    __shared__ short Ps[8][16][68];
    const int tid = threadIdx.x;
    const int wave = tid >> 6, lane = tid & 63;
    const int quad = lane >> 4, l16 = lane & 15;
    const int bh = blockIdx.x, b = bh >> 3, h = bh & 7;
    const int p = blockIdx.y;                    // 0..7
    const int w = wave & 3;
    const bool gA = wave < 4;
    const int q2t = 15 - p;
    const int rb1 = p * 64 + w * 16, rb2 = q2t * 64 + w * 16;
    short* PsW = &Ps[wave][0][0];
    const int tidg = tid & 255;

    short (*Kc)[264] = gA ? KcA : KcB;
    short (*Ksf)[72] = gA ? KsfA : KsfB;
    short (*Vv)[72]  = gA ? VbA : VbB;

    // q for current stream (A: q1 rows; B: q2 rows)
    s8 qc[8], qs[2];
    {
        const int rq = gA ? rb1 : rb2;
        const bf16* qp = x2y + (size_t)(bh * T_ + rq + l16) * M_ + quad * 8;
        #pragma unroll
        for (int f = 0; f < 8; ++f) qc[f] = *(const s8*)(qp + f * 32);
        const bf16* qsp = qkv_x + (size_t)(b * T_ + rq + l16) * C3_ + h * HD_ + quad * 8;
        qs[0] = *(const s8*)qsp;
        qs[1] = *(const s8*)(qsp + 32);
    }

    // dense cross part for own output rows (A: q1, B: q2)
    f4 ocv[4];
    #pragma unroll
    for (int dt = 0; dt < 4; ++dt) ocv[dt] = (f4)0.f;
    {
        const bf16* vb = vTy + (size_t)(bh * 64 + l16) * M_ + quad * 8;
        #pragma unroll
        for (int f = 0; f < 8; ++f)
            #pragma unroll
            for (int dt = 0; dt < 4; ++dt) {
                s8 bv = *(const s8*)(vb + (size_t)dt * 16 * M_ + f * 32);
                ocv[dt] = MFMA16(qc[f], bv, ocv[dt]);
            }
    }

    f4 oc[4], os_[4];
    float lc[4] = {0.f, 0.f, 0.f, 0.f}, ls_[4] = {0.f, 0.f, 0.f, 0.f};
    #pragma unroll
    for (int dt = 0; dt < 4; ++dt) { oc[dt] = (f4)0.f; os_[dt] = (f4)0.f; }

    // initial stage: A loads tile 0 into bufA, B loads tile 8-p into bufB
    {
        const int s = gA ? 0 : (8 - p);
        #pragma unroll
        for (int tl = 0; tl < 8; ++tl) {
            int g = tidg + tl * 256, row = g >> 5, grp = g & 31;
            *(s8*)&Kc[row][grp * 8] = *(const s8*)&y2x[(size_t)(bh * T_ + s * 64 + row) * M_ + grp * 8];
        }
        #pragma unroll
        for (int tl = 0; tl < 2; ++tl) {
            int g = tidg + tl * 256, row = g >> 3, grp = g & 7;
            *(s8*)&Ksf[row][grp * 8] =
                *(const s8*)&qkv_x[(size_t)(b * T_ + s * 64 + row) * C3_ + C_ + h * HD_ + grp * 8];
            *(s8*)&Vv[row][grp * 8] = *(const s8*)&vTx[(size_t)(bh * 64 + row) * T_ + s * 64 + grp * 8];
        }
    }
    __syncthreads();

    for (int ph = 0; ph < 9; ++ph) {
        // my tile this phase
        int s, trow; bool active, diag;
        if (gA) {
            if (ph <= p) { s = ph;         diag = (ph == p); trow = rb1; }
            else         { s = ph - p - 1; diag = false;     trow = rb2; }
            active = true;
        } else {
            s = 8 - p + ph; diag = (ph == 7); trow = rb2;
            active = (ph < 8);
        }
        // tile to stage for next phase
        int sn;
        if (gA) sn = (ph < p) ? (ph + 1) : ((ph == p) ? 0 : ((ph < 8) ? (ph - p) : -1));
        else    sn = (ph < 7) ? (s + 1) : -1;

        s8 kc[8], ks[2], vb[2];
        if (sn >= 0) {
            #pragma unroll
            for (int tl = 0; tl < 8; ++tl) {
                int g = tidg + tl * 256, row = g >> 5, grp = g & 31;
                kc[tl] = *(const s8*)&y2x[(size_t)(bh * T_ + sn * 64 + row) * M_ + grp * 8];
            }
            #pragma unroll
            for (int tl = 0; tl < 2; ++tl) {
                int g = tidg + tl * 256, row = g >> 3, grp = g & 7;
                ks[tl] = *(const s8*)&qkv_x[(size_t)(b * T_ + sn * 64 + row) * C3_ + C_ + h * HD_ + grp * 8];
                vb[tl] = *(const s8*)&vTx[(size_t)(bh * 64 + row) * T_ + sn * 64 + grp * 8];
            }
        }

        if (active)
            attn_unit(&Kc[0][0], &Ksf[0][0], &Vv[0][0], PsW, qc, qs,
                      oc, os_, lc, ls_, s * 64, diag, trow, quad, l16);

        // A's q1 -> q2 stream switch: epilogue q1, reload q for q2, zero accumulators.
        // (no barriers inside; pure data divergence)
        if (gA && ph == p) {
            #pragma unroll
            for (int reg = 0; reg < 4; ++reg) {
                float l1 = lc[reg], l2 = ls_[reg];
                l1 += __shfl_xor(l1, 1); l1 += __shfl_xor(l1, 2);
                l1 += __shfl_xor(l1, 4); l1 += __shfl_xor(l1, 8);
                l2 += __shfl_xor(l2, 1); l2 += __shfl_xor(l2, 2);
                l2 += __shfl_xor(l2, 4); l2 += __shfl_xor(l2, 8);
                const float i1 = 1.f / l1, i2 = 1.f / l2;
                const int t = rb1 + quad * 4 + reg;
                #pragma unroll
                for (int dt = 0; dt < 4; ++dt) {
                    size_t idx = (size_t)(b * T_ + t) * C_ + h * HD_ + dt * 16 + l16;
                    cval_bf[idx] = __float2bfloat16(ocv[dt][reg] + oc[dt][reg] * i1 + x[idx]);
                    sval_bf[idx] = __float2bfloat16(os_[dt][reg] * i2);
                }
            }
            const bf16* qp = x2y + (size_t)(bh * T_ + rb2 + l16) * M_ + quad * 8;
            #pragma unroll
            for (int f = 0; f < 8; ++f) qc[f] = *(const s8*)(qp + f * 32);
            const bf16* qsp = qkv_x + (size_t)(b * T_ + rb2 + l16) * C3_ + h * HD_ + quad * 8;
            qs[0] = *(const s8*)qsp;
            qs[1] = *(const s8*)(qsp + 32);
            #pragma unroll
            for (int dt = 0; dt < 4; ++dt) { oc[dt] = (f4)0.f; os_[dt] = (f4)0.f; }
            #pragma unroll
            for (int reg = 0; reg < 4; ++reg) { lc[reg] = 0.f; ls_[reg] = 0.f; }
        }

        __syncthreads();   // all reads of buffers complete
        if (sn >= 0) {
            #pragma unroll
            for (int tl = 0; tl < 8; ++tl) {
                int g = tidg + tl * 256, row = g >> 5, grp = g & 31;
                *(s8*)&Kc[row][grp * 8] = kc[tl];
            }
            #pragma unroll
            for (int tl = 0; tl < 2; ++tl) {
                int g = tidg + tl * 256, row = g >> 3, grp = g & 7;
                *(s8*)&Ksf[row][grp * 8] = ks[tl];
                *(s8*)&Vv[row][grp * 8] = vb[tl];
            }
        }
        __syncthreads();   // new tile visible
    }

    // A publishes q2 partials into (dead) bufA; one uniform barrier; B merges + epilogue.
    if (gA) {
        float* fb = (float*)&KcA[0][0];
        float* lb = (float*)&KsfA[0][0];
        const int base = w * 64 + lane;
        #pragma unroll
        for (int dt = 0; dt < 4; ++dt)
            #pragma unroll
            for (int reg = 0; reg < 4; ++reg) {
                fb[base * 33 + dt * 4 + reg] = oc[dt][reg];
                fb[base * 33 + 16 + dt * 4 + reg] = os_[dt][reg];
            }
        #pragma unroll
        for (int reg = 0; reg < 4; ++reg) {
            lb[base * 9 + reg] = lc[reg];
            lb[base * 9 + 4 + reg] = ls_[reg];
        }
    }
    __syncthreads();
    if (!gA) {
        const float* fb = (const float*)&KcA[0][0];
        const float* lb = (const float*)&KsfA[0][0];
        const int base = w * 64 + lane;
        #pragma unroll
        for (int dt = 0; dt < 4; ++dt)
            #pragma unroll
            for (int reg = 0; reg < 4; ++reg) {
                oc[dt][reg] += fb[base * 33 + dt * 4 + reg];
                os_[dt][reg] += fb[base * 33 + 16 + dt * 4 + reg];
            }
        #pragma unroll
        for (int reg = 0; reg < 4; ++reg) {
            lc[reg] += lb[base * 9 + reg];
            ls_[reg] += lb[base * 9 + 4 + reg];
        }
        #pragma unroll
        for (int reg = 0; reg < 4; ++reg) {
            float l1 = lc[reg], l2 = ls_[reg];
            l1 += __shfl_xor(l1, 1); l1 += __shfl_xor(l1, 2);
            l1 += __shfl_xor(l1, 4); l1 += __shfl_xor(l1, 8);
            l2 += __shfl_xor(l2, 1); l2 += __shfl_xor(l2, 2);
            l2 += __shfl_xor(l2, 4); l2 += __shfl_xor(l2, 8);
            const float i1 = 1.f / l1, i2 = 1.f / l2;
            const int t = rb2 + quad * 4 + reg;
            #pragma unroll
            for (int dt = 0; dt < 4; ++dt) {
                size_t idx = (size_t)(b * T_ + t) * C_ + h * HD_ + dt * 16 + l16;
                cval_bf[idx] = __float2bfloat16(ocv[dt][reg] + oc[dt][reg] * i1 + x[idx]);
                sval_bf[idx] = __float2bfloat16(os_[dt][reg] * i2);
            }
        }
    }
}

// ---------------- fused dual gate GEMM + sigmoid + combine -> gated bf16 ----------------
__global__ __launch_bounds__(256) void gatefuse_kernel(
    const bf16* __restrict__ svalb, const bf16* __restrict__ cvalb,
    const bf16* __restrict__ WTgs, const bf16* __restrict__ WTgc,
    const float* __restrict__ bgs, const float* __restrict__ bgc,
    bf16* __restrict__ gated)
{
    __shared__ short Sb[128][72], Cb[128][72], W1b[64][72], W2b[64][72];
    const int tid = threadIdx.x;
    const int wave = tid >> 6, lane = tid & 63;
    const int quad = lane >> 4, l16 = lane & 15;
    const int n0 = blockIdx.y * 64, m0 = blockIdx.x * 128;
    f4 aS[2][4], aC[2][4];
    #pragma unroll
    for (int mt = 0; mt < 2; ++mt)
        #pragma unroll
        for (int nt = 0; nt < 4; ++nt) { aS[mt][nt] = (f4)0.f; aC[mt][nt] = (f4)0.f; }

    for (int k0 = 0; k0 < C_; k0 += 64) {
        #pragma unroll
        for (int tl = 0; tl < 4; ++tl) {
            int g = tid + tl * 256, row = g >> 3, grp = g & 7;
            *(s8*)&Sb[row][grp * 8] = *(const s8*)&svalb[(size_t)(m0 + row) * C_ + k0 + grp * 8];
            *(s8*)&Cb[row][grp * 8] = *(const s8*)&cvalb[(size_t)(m0 + row) * C_ + k0 + grp * 8];
        }
        #pragma unroll
        for (int tl = 0; tl < 2; ++tl) {
            int g = tid + tl * 256, n = g >> 3, grp = g & 7;
            *(s8*)&W1b[n][grp * 8] = *(const s8*)&WTgs[(size_t)(n0 + n) * C_ + k0 + grp * 8];
            *(s8*)&W2b[n][grp * 8] = *(const s8*)&WTgc[(size_t)(n0 + n) * C_ + k0 + grp * 8];
        }
        __syncthreads();
        #pragma unroll
        for (int ks = 0; ks < 2; ++ks) {
            s8 s0f = *(const s8*)&Sb[wave * 32 + l16][ks * 32 + quad * 8];
            s8 s1f = *(const s8*)&Sb[wave * 32 + 16 + l16][ks * 32 + quad * 8];
            s8 c0f = *(const s8*)&Cb[wave * 32 + l16][ks * 32 + quad * 8];
            s8 c1f = *(const s8*)&Cb[wave * 32 + 16 + l16][ks * 32 + quad * 8];
            #pragma unroll
            for (int nt = 0; nt < 4; ++nt) {
                s8 w1 = *(const s8*)&W1b[nt * 16 + l16][ks * 32 + quad * 8];
                s8 w2 = *(const s8*)&W2b[nt * 16 + l16][ks * 32 + quad * 8];
                aS[0][nt] = MFMA16(s0f, w1, aS[0][nt]);
                aS[1][nt] = MFMA16(s1f, w1, aS[1][nt]);
                aC[0][nt] = MFMA16(c0f, w2, aC[0][nt]);
                aC[1][nt] = MFMA16(c1f, w2, aC[1][nt]);
            }
        }
        __syncthreads();
    }
    #pragma unroll
    for (int mt = 0; mt < 2; ++mt)
        #pragma unroll
        for (int nt = 0; nt < 4; ++nt) {
            int col = n0 + nt * 16 + l16;
            float b1 = bgs[col], b2 = bgc[col];
            #pragma unroll
            for (int reg = 0; reg < 4; ++reg) {
                int row = m0 + wave * 32 + mt * 16 + quad * 4 + reg;
                size_t idx = (size_t)row * C_ + col;
                float gs = 1.f / (1.f + __expf(-(aS[mt][nt][reg] + b1)));
                float gc = 1.f / (1.f + __expf(-(aC[mt][nt][reg] + b2)));
                float cvv = __bfloat162float(cvalb[idx]);
                float svv = __bfloat162float(svalb[idx]);
                gated[idx] = __float2bfloat16(gs * cvv + gc * svv);
            }
        }
}

extern "C" void kernel_launch(void* const* d_in, const int* in_sizes, int n_in,
                              void* d_out, int out_size, void* d_ws, size_t ws_size,
                              hipStream_t stream)
{
    const float* x      = (const float*)d_in[0];
    const float* y      = (const float*)d_in[1];
    // d_in[2]: attn_x_mask — structurally causal tril, computed inline
    const float* Wqkv_x = (const float*)d_in[3];
    const float* bqkv_x = (const float*)d_in[4];
    const float* Wqkv_y = (const float*)d_in[5];
    const float* bqkv_y = (const float*)d_in[6];
    const float* w4x    = (const float*)d_in[7];
    const float* w4y    = (const float*)d_in[8];
    const float* w4xy   = (const float*)d_in[9];
    const float* Wgs    = (const float*)d_in[10];
    const float* bgs    = (const float*)d_in[11];
    const float* Wgc    = (const float*)d_in[12];
    const float* bgc    = (const float*)d_in[13];
    const float* Wp     = (const float*)d_in[14];
    const float* bp     = (const float*)d_in[15];

    // Workspace (f-word offsets; proven layout)
    float* ws = (float*)d_ws;
    bf16*  qkv_x_bf = (bf16*)(ws + 0);           // 6,291,456 bf16
    bf16*  qkv_y_bf = (bf16*)(ws + 3145728);     // 1,572,864 bf16
    bf16*  gated_bf = (bf16*)(ws + 3932160);
    bf16*  cval_bf  = (bf16*)(ws + 5242880);
    bf16*  x2y_bf   = (bf16*)(ws + 12320768);    // 8,388,608 bf16 (written by catt3r)
    bf16*  x_bf     = x2y_bf;                    //   pre-QKV reuse
    bf16*  y_bf     = (bf16*)(ws + 13369344);    //   pre-QKV reuse
    bf16*  y2x_bf   = (bf16*)(ws + 16515072);    // 8,388,608 bf16 (written by y2xw)
    bf16*  vTx_bf   = (bf16*)(ws + 20709376);    // 2,097,152 bf16
    bf16*  vTy_bf   = (bf16*)(ws + 21757952);    // 524,288 bf16
    float* psum_    = ws + 22020096;             // 131,072 f
    bf16*  qw_bf    = (bf16*)(ws + 26214400);    // 2,097,152 bf16 (dead after catt3r)
    bf16*  sval_bf  = qw_bf;                     //   reuse
    bf16*  WT_x     = (bf16*)(ws + 27262976);    // 786,432 bf16
    bf16*  WT_y     = (bf16*)(ws + 27656192);
    bf16*  WT_gs    = (bf16*)(ws + 28049408);    // 262,144 bf16
    bf16*  WT_gc    = (bf16*)(ws + 28180480);
    bf16*  WT_p    = (bf16*)(ws + 28311552);
    float* catt1b   = ws + 28442624;             // 32,768 f
    float* catt2b   = ws + 28475392;             //  8,192 f
    float* colinv   = ws + 28483584;             //  8,192 f
    float* rowsum_  = ws + 28491776;             // 32,768 f

    // 0: one prep dispatch
    prep_kernel<<<1856, 256, 0, stream>>>(
        Wqkv_x, Wqkv_y, Wgs, Wgc, Wp, x, y,
        WT_x, WT_y, WT_gs, WT_gc, WT_p, x_bf, y_bf);

    // 1-2: QKV projections
    gemm_staged_kernel<bf16><<<dim3(32, 24), 256, 0, stream>>>(x_bf, WT_x, bqkv_x, qkv_x_bf, C3_, C_);
    gemm_staged_kernel<bf16><<<dim3(8, 24), 256, 0, stream>>>(y_bf, WT_y, bqkv_y, qkv_y_bf, C3_, C_);

    // 3: catt1/catt2/qw
    qwcatt_kernel<<<1184, 256, 0, stream>>>(
        qkv_x_bf, qkv_y_bf, w4x, w4y, w4xy, catt1b, catt2b, qw_bf);

    // 4: fused logits + row softmax -> x2y + rowsum + col partials
    catt3r_kernel<<<dim3(32, 16), 256, 0, stream>>>(
        qw_bf, qkv_y_bf, catt1b, catt2b, x2y_bf, rowsum_, psum_);

    // 5: colfin + V transposes
    colfin_vtrans_kernel<<<672, 256, 0, stream>>>(psum_, colinv, qkv_x_bf, qkv_y_bf, vTx_bf, vTy_bf);

    // 6: y2x = x2y * rowsum * colinv
    y2xw_kernel<<<4096, 256, 0, stream>>>(x2y_bf, rowsum_, colinv, y2x_bf);

    // 7: split-assist balanced flash (barrier-uniform 9-phase schedule)
    flash11_kernel<<<dim3(32, 8), 512, 0, stream>>>(
        x2y_bf, y2x_bf, vTx_bf, vTy_bf, qkv_x_bf, x, cval_bf, sval_bf);

    // 8: fused gates (bf16 elementwise)
    gatefuse_kernel<<<dim3(32, 8), 256, 0, stream>>>(
        sval_bf, cval_bf, WT_gs, WT_gc, bgs, bgc, gated_bf);

    // 9: out = gated @ Wp + bp
    gemm_staged_kernel<float><<<dim3(32, 8), 256, 0, stream>>>(
        gated_bf, WT_p, bp, (float*)d_out, C_, C_);
}

// Round 5
// 221.400 us; speedup vs baseline: 1.0866x; 1.0350x over previous
//
#include <hip/hip_runtime.h>
#include <hip/hip_bf16.h>

typedef __hip_bfloat16 bf16;
using f4 = __attribute__((ext_vector_type(4))) float;
using s8 = __attribute__((ext_vector_type(8))) short;
using s4 = __attribute__((ext_vector_type(4))) short;

__device__ __forceinline__ void storeOut(float* p, float v) { *p = v; }
__device__ __forceinline__ void storeOut(bf16* p, float v) { *p = __float2bfloat16(v); }
__device__ __forceinline__ short bfs(float x) { return __builtin_bit_cast(short, __float2bfloat16(x)); }

constexpr int B_ = 4, T_ = 1024, M_ = 256, C_ = 512, H_ = 8, HD_ = 64, C3_ = 1536;

#define MFMA16(a, b, c) __builtin_amdgcn_mfma_f32_16x16x32_bf16((a), (b), (c), 0, 0, 0)

// ---------------- prep: 5 weight transposes (fp32 KxN -> bf16 NxK) + 2 converts ----------------
__global__ __launch_bounds__(256) void prep_kernel(
    const float* __restrict__ Wqkv_x, const float* __restrict__ Wqkv_y,
    const float* __restrict__ Wgs, const float* __restrict__ Wgc, const float* __restrict__ Wp,
    const float* __restrict__ x, const float* __restrict__ y,
    bf16* __restrict__ WT_x, bf16* __restrict__ WT_y, bf16* __restrict__ WT_gs,
    bf16* __restrict__ WT_gc, bf16* __restrict__ WT_p,
    bf16* __restrict__ x_bf, bf16* __restrict__ y_bf)
{
    __shared__ float Ls[64][65];
    const int tid = threadIdx.x;
    const int bid = blockIdx.x;
    if (bid < 576) {
        const float* W; bf16* WT; int N, t;
        if (bid < 192)      { W = Wqkv_x; WT = WT_x;  N = C3_; t = bid; }
        else if (bid < 384) { W = Wqkv_y; WT = WT_y;  N = C3_; t = bid - 192; }
        else if (bid < 448) { W = Wgs;    WT = WT_gs; N = C_;  t = bid - 384; }
        else if (bid < 512) { W = Wgc;    WT = WT_gc; N = C_;  t = bid - 448; }
        else                { W = Wp;     WT = WT_p;  N = C_;  t = bid - 512; }
        const int K = C_;
        const int tw = N >> 6;
        const int n0 = (t % tw) * 64, k0 = (t / tw) * 64;
        for (int i = tid; i < 1024; i += 256) {
            int kr = i >> 4, ng = i & 15;
            float4 v = *(const float4*)&W[(size_t)(k0 + kr) * N + n0 + ng * 4];
            Ls[ng * 4 + 0][kr] = v.x; Ls[ng * 4 + 1][kr] = v.y;
            Ls[ng * 4 + 2][kr] = v.z; Ls[ng * 4 + 3][kr] = v.w;
        }
        __syncthreads();
        for (int i = tid; i < 512; i += 256) {
            int n = i >> 3, kg = i & 7;
            s8 r;
            #pragma unroll
            for (int j = 0; j < 8; ++j) r[j] = bfs(Ls[n][kg * 8 + j]);
            *(s8*)&WT[(size_t)(n0 + n) * K + k0 + kg * 8] = r;
        }
    } else if (bid < 1600) {
        int i = (bid - 576) * 2048 + tid * 8;
        s8 r;
        #pragma unroll
        for (int j = 0; j < 8; ++j) r[j] = bfs(x[i + j]);
        *(s8*)&x_bf[i] = r;
    } else {
        int i = (bid - 1600) * 2048 + tid * 8;
        s8 r;
        #pragma unroll
        for (int j = 0; j < 8; ++j) r[j] = bfs(y[i + j]);
        *(s8*)&y_bf[i] = r;
    }
}

// ---------------- merged catt1/catt2 + qw (one dispatch) ----------------
__global__ __launch_bounds__(256) void qwcatt_kernel(
    const bf16* __restrict__ qkv_x, const bf16* __restrict__ qkv_y,
    const float* __restrict__ w4x, const float* __restrict__ w4y,
    const float* __restrict__ w4xy,
    float* __restrict__ catt1b, float* __restrict__ catt2b, bf16* __restrict__ qw)
{
    const int bid = blockIdx.x;
    const int tid = threadIdx.x;
    if (bid < 160) {
        int i = bid * 256 + tid;   // 0..40959
        const bf16* row; const float* w; float* out; int oi;
        if (i < 32768) {
            int bh = i >> 10, t = i & 1023, b = bh >> 3, h = bh & 7;
            row = qkv_x + (size_t)(b * T_ + t) * C3_ + h * HD_;
            w = w4x + h * HD_; out = catt1b; oi = i;
        } else {
            int j = i - 32768;
            int bh = j >> 8, m = j & 255, b = bh >> 3, h = bh & 7;
            row = qkv_y + (size_t)(b * M_ + m) * C3_ + h * HD_;
            w = w4y + h * HD_; out = catt2b; oi = j;
        }
        float s = 0.f;
        #pragma unroll
        for (int d = 0; d < HD_; ++d) s = fmaf(__bfloat162float(row[d]), w[d], s);
        out[oi] = s;
    } else {
        int o = ((bid - 160) * 256 + tid) * 8;
        int row = o >> 9, c = o & 511;
        const bf16* src = qkv_x + (size_t)row * C3_ + c;
        s8 r;
        #pragma unroll
        for (int j = 0; j < 8; ++j) r[j] = bfs(__bfloat162float(src[j]) * w4xy[c + j]);
        *(s8*)&qw[o] = r;
    }
}

// ---------------- LDS-staged MFMA GEMM (m-major grid) ----------------
template <typename OT>
__global__ __launch_bounds__(256) void gemm_staged_kernel(
    const bf16* __restrict__ A, const bf16* __restrict__ WT, const float* __restrict__ bias,
    OT* __restrict__ Cmat, int N, int K)
{
    __shared__ short Asb[128][72];
    __shared__ short Bsb[64][72];
    const int tid = threadIdx.x;
    const int wave = tid >> 6, lane = tid & 63;
    const int quad = lane >> 4, l16 = lane & 15;
    const int n0 = blockIdx.y * 64, m0 = blockIdx.x * 128;
    f4 acc[2][4];
    #pragma unroll
    for (int mt = 0; mt < 2; ++mt)
        #pragma unroll
        for (int nt = 0; nt < 4; ++nt) acc[mt][nt] = (f4)0.f;

    for (int k0 = 0; k0 < K; k0 += 64) {
        #pragma unroll
        for (int tl = 0; tl < 4; ++tl) {
            int g = tid + tl * 256, row = g >> 3, grp = g & 7;
            *(s8*)&Asb[row][grp * 8] = *(const s8*)&A[(size_t)(m0 + row) * K + k0 + grp * 8];
        }
        #pragma unroll
        for (int tl = 0; tl < 2; ++tl) {
            int g = tid + tl * 256, n = g >> 3, grp = g & 7;
            *(s8*)&Bsb[n][grp * 8] = *(const s8*)&WT[(size_t)(n0 + n) * K + k0 + grp * 8];
        }
        __syncthreads();
        #pragma unroll
        for (int ks = 0; ks < 2; ++ks) {
            s8 a0 = *(const s8*)&Asb[wave * 32 + l16][ks * 32 + quad * 8];
            s8 a1 = *(const s8*)&Asb[wave * 32 + 16 + l16][ks * 32 + quad * 8];
            #pragma unroll
            for (int nt = 0; nt < 4; ++nt) {
                s8 bv = *(const s8*)&Bsb[nt * 16 + l16][ks * 32 + quad * 8];
                acc[0][nt] = MFMA16(a0, bv, acc[0][nt]);
                acc[1][nt] = MFMA16(a1, bv, acc[1][nt]);
            }
        }
        __syncthreads();
    }
    #pragma unroll
    for (int mt = 0; mt < 2; ++mt)
        #pragma unroll
        for (int nt = 0; nt < 4; ++nt) {
            int col = n0 + nt * 16 + l16;
            float bb = bias[col];
            #pragma unroll
            for (int reg = 0; reg < 4; ++reg) {
                int row = m0 + wave * 32 + mt * 16 + quad * 4 + reg;
                storeOut(&Cmat[(size_t)row * N + col], acc[mt][nt][reg] + bb);
            }
        }
}

// ---------------- catt3r: logits + row softmax -> x2y bf16 + rowsum + col partial sums ----------------
__global__ __launch_bounds__(256) void catt3r_kernel(
    const bf16* __restrict__ qw, const bf16* __restrict__ qkv_y,
    const float* __restrict__ catt1, const float* __restrict__ catt2,
    bf16* __restrict__ x2y, float* __restrict__ rowsum_, float* __restrict__ psum)
{
    __shared__ float redc[4][256];
    const int tid = threadIdx.x;
    const int wave = tid >> 6, lane = tid & 63;
    const int quad = lane >> 4, l16 = lane & 15;
    const int bh = blockIdx.x, b = bh >> 3, h = bh & 7;
    const int t0 = blockIdx.y * 64;
    f4 sc[4][4];
    #pragma unroll
    for (int mt = 0; mt < 4; ++mt)
        #pragma unroll
        for (int nt = 0; nt < 4; ++nt) sc[mt][nt] = (f4)0.f;

    const bf16* ap = qw + (size_t)(b * T_ + t0 + wave * 16 + l16) * C_ + h * HD_ + quad * 8;
    s8 a0 = *(const s8*)ap;
    s8 a1 = *(const s8*)(ap + 32);
    const bf16* bp = qkv_y + (size_t)(b * M_ + l16) * C3_ + C_ + h * HD_ + quad * 8;
    #pragma unroll
    for (int mt = 0; mt < 4; ++mt)
        #pragma unroll
        for (int nt = 0; nt < 4; ++nt) {
            const bf16* bq = bp + (size_t)(mt * 64 + nt * 16) * C3_;
            sc[mt][nt] = MFMA16(a0, *(const s8*)bq, sc[mt][nt]);
            sc[mt][nt] = MFMA16(a1, *(const s8*)(bq + 32), sc[mt][nt]);
        }

    float c1[4];
    #pragma unroll
    for (int reg = 0; reg < 4; ++reg)
        c1[reg] = catt1[bh * T_ + t0 + wave * 16 + quad * 4 + reg];
    #pragma unroll
    for (int mt = 0; mt < 4; ++mt)
        #pragma unroll
        for (int nt = 0; nt < 4; ++nt) {
            float c2 = catt2[bh * M_ + mt * 64 + nt * 16 + l16];
            #pragma unroll
            for (int reg = 0; reg < 4; ++reg)
                sc[mt][nt][reg] = __expf(sc[mt][nt][reg] * 0.125f + c1[reg] + c2);
        }

    #pragma unroll
    for (int reg = 0; reg < 4; ++reg) {
        float rs = 0.f;
        #pragma unroll
        for (int mt = 0; mt < 4; ++mt)
            #pragma unroll
            for (int nt = 0; nt < 4; ++nt) rs += sc[mt][nt][reg];
        rs += __shfl_xor(rs, 1); rs += __shfl_xor(rs, 2);
        rs += __shfl_xor(rs, 4); rs += __shfl_xor(rs, 8);
        const int t = t0 + wave * 16 + quad * 4 + reg;
        if (l16 == 0) rowsum_[bh * T_ + t] = rs;
        const float ri = 1.f / rs;
        #pragma unroll
        for (int mt = 0; mt < 4; ++mt)
            #pragma unroll
            for (int nt = 0; nt < 4; ++nt)
                x2y[((size_t)bh * T_ + t) * M_ + mt * 64 + nt * 16 + l16] =
                    __float2bfloat16(sc[mt][nt][reg] * ri);
    }

    #pragma unroll
    for (int mt = 0; mt < 4; ++mt)
        #pragma unroll
        for (int nt = 0; nt < 4; ++nt) {
            float es = sc[mt][nt][0] + sc[mt][nt][1] + sc[mt][nt][2] + sc[mt][nt][3];
            es += __shfl_xor(es, 16);
            es += __shfl_xor(es, 32);
            if (quad == 0) redc[wave][mt * 64 + nt * 16 + l16] = es;
        }
    __syncthreads();
    psum[((size_t)bh * 16 + blockIdx.y) * M_ + tid] =
        redc[0][tid] + redc[1][tid] + redc[2][tid] + redc[3][tid];
}

// ---------------- merged colfin + V transposes (one dispatch) ----------------
__global__ __launch_bounds__(256) void colfin_vtrans_kernel(
    const float* __restrict__ psum, float* __restrict__ colinv,
    const bf16* __restrict__ qkv_x, const bf16* __restrict__ qkv_y,
    bf16* __restrict__ vTx, bf16* __restrict__ vTy)
{
    __shared__ short Ls[64][68];
    const int tid = threadIdx.x;
    int bid = blockIdx.x;
    if (bid < 32) {
        const int bh = bid, m = tid;
        float s = 0.f;
        #pragma unroll
        for (int ch = 0; ch < 16; ++ch) s += psum[(bh * 16 + ch) * M_ + m];
        colinv[bh * M_ + m] = 1.f / s;
        return;
    }
    bid -= 32;
    const bf16* qkv; bf16* vT; int Nrows, bh, t0;
    if (bid < 512) { qkv = qkv_x; vT = vTx; Nrows = T_; bh = bid >> 4; t0 = (bid & 15) * 64; }
    else { bid -= 512; qkv = qkv_y; vT = vTy; Nrows = M_; bh = bid >> 2; t0 = (bid & 3) * 64; }
    const int b = bh >> 3, h = bh & 7;
    for (int i = tid; i < 4096; i += 256) {
        int tl = i >> 6, d = i & 63;
        Ls[d][tl] = __builtin_bit_cast(short,
            qkv[(size_t)(b * Nrows + t0 + tl) * C3_ + 2 * C_ + h * HD_ + d]);
    }
    __syncthreads();
    for (int i = tid; i < 4096; i += 256) {
        int d = i >> 6, tl = i & 63;
        vT[((size_t)bh * 64 + d) * Nrows + t0 + tl] = __builtin_bit_cast(bf16, Ls[d][tl]);
    }
}

// ---------------- y2xw: y2x = x2y * rowsum * colinv ----------------
__global__ __launch_bounds__(256) void y2xw_kernel(
    const bf16* __restrict__ x2y, const float* __restrict__ rowsum_,
    const float* __restrict__ colinv, bf16* __restrict__ y2x)
{
    const int i = (blockIdx.x * 256 + threadIdx.x) * 8;
    const int row = i >> 8, m = i & 255, bh = row >> 10;
    const float rs = rowsum_[row];
    s8 v = *(const s8*)&x2y[i];
    const float4 c0 = *(const float4*)&colinv[bh * M_ + m];
    const float4 c4 = *(const float4*)&colinv[bh * M_ + m + 4];
    float ci[8] = {c0.x, c0.y, c0.z, c0.w, c4.x, c4.y, c4.z, c4.w};
    s8 r;
    #pragma unroll
    for (int j = 0; j < 8; ++j)
        r[j] = bfs(__bfloat162float(__builtin_bit_cast(bf16, v[j])) * rs * ci[j]);
    *(s8*)&y2x[i] = r;
}

// ---------------- flash12: flash8 verbatim (grid 32x8, 512 thr, paired jt, Ps inner
// pipeline, same staging index math) + double-buffered Kc/Ksf/Vb with ONE barrier per
// iteration. buf[nxt] was last read at iter st-1, whose end-of-iter barrier already
// retired those reads -> the ds_write needs no pre-barrier and overlaps compute.
// Barrier drains per block: 32 -> 16. ----------------
__global__ __launch_bounds__(512) void flash12_kernel(
    const bf16* __restrict__ x2y, const bf16* __restrict__ y2x,
    const bf16* __restrict__ vTx, const bf16* __restrict__ vTy,
    const bf16* __restrict__ qkv_x, const float* __restrict__ x,
    bf16* __restrict__ cval_bf, bf16* __restrict__ sval_bf)
{
    __shared__ short Kc[2][64][264];
    __shared__ short Ksf[2][64][72];
    __shared__ short Vb[2][64][72];
    __shared__ short Ps[8][16][68];
    const int tid = threadIdx.x;
    const int wave = tid >> 6, lane = tid & 63;
    const int quad = lane >> 4, l16 = lane & 15;
    const int bh = blockIdx.x, b = bh >> 3, h = bh & 7;
    const int p = blockIdx.y;
    const int jt = (wave < 4) ? p : (15 - p);
    const int rb = jt * 64 + (wave & 3) * 16;
    const int nst = 16 - p;

    s8 qc[8], qs[2];
    {
        const bf16* qp = x2y + (size_t)(bh * T_ + rb + l16) * M_ + quad * 8;
        #pragma unroll
        for (int f = 0; f < 8; ++f) qc[f] = *(const s8*)(qp + f * 32);
        const bf16* qsp = qkv_x + (size_t)(b * T_ + rb + l16) * C3_ + h * HD_ + quad * 8;
        qs[0] = *(const s8*)qsp;
        qs[1] = *(const s8*)(qsp + 32);
    }

    f4 ocv[4];
    #pragma unroll
    for (int dt = 0; dt < 4; ++dt) ocv[dt] = (f4)0.f;
    {
        const bf16* vb = vTy + (size_t)(bh * 64 + l16) * M_ + quad * 8;
        #pragma unroll
        for (int f = 0; f < 8; ++f)
            #pragma unroll
            for (int dt = 0; dt < 4; ++dt) {
                s8 bv = *(const s8*)(vb + (size_t)dt * 16 * M_ + f * 32);
                ocv[dt] = MFMA16(qc[f], bv, ocv[dt]);
            }
    }

    f4 oc[4], os_[4];
    float lc[4] = {0.f, 0.f, 0.f, 0.f}, ls_[4] = {0.f, 0.f, 0.f, 0.f};
    #pragma unroll
    for (int dt = 0; dt < 4; ++dt) { oc[dt] = (f4)0.f; os_[dt] = (f4)0.f; }

    // stage s-tile 0 into buf 0
    #pragma unroll
    for (int tl = 0; tl < 4; ++tl) {
        int g = tid + tl * 512, row = g >> 5, grp = g & 31;
        *(s8*)&Kc[0][row][grp * 8] = *(const s8*)&y2x[(size_t)(bh * T_ + row) * M_ + grp * 8];
    }
    {
        int row = tid >> 3, grp = tid & 7;
        *(s8*)&Ksf[0][row][grp * 8] =
            *(const s8*)&qkv_x[(size_t)(b * T_ + row) * C3_ + C_ + h * HD_ + grp * 8];
        *(s8*)&Vb[0][row][grp * 8] = *(const s8*)&vTx[(size_t)(bh * 64 + row) * T_ + grp * 8];
    }
    __syncthreads();

    for (int st = 0; st < nst; ++st) {
        const int cur = st & 1, nxt = cur ^ 1;
        const int s0 = st * 64;
        const bool pf = (st + 1) < nst;
        s8 kcp[4], ksp, vp;
        if (pf) {
            const int sn = s0 + 64;
            #pragma unroll
            for (int tl = 0; tl < 4; ++tl) {
                int g = tid + tl * 512, row = g >> 5, grp = g & 31;
                kcp[tl] = *(const s8*)&y2x[(size_t)(bh * T_ + sn + row) * M_ + grp * 8];
            }
            int row = tid >> 3, grp = tid & 7;
            ksp = *(const s8*)&qkv_x[(size_t)(b * T_ + sn + row) * C3_ + C_ + h * HD_ + grp * 8];
            vp = *(const s8*)&vTx[(size_t)(bh * 64 + row) * T_ + sn + grp * 8];
        }
        if (st <= jt) {
            f4 sc[4];
            #pragma unroll
            for (int nt = 0; nt < 4; ++nt) sc[nt] = (f4)0.f;
            #pragma unroll
            for (int f = 0; f < 8; ++f)
                #pragma unroll
                for (int nt = 0; nt < 4; ++nt) {
                    s8 bv = *(const s8*)&Kc[cur][nt * 16 + l16][f * 32 + quad * 8];
                    sc[nt] = MFMA16(qc[f], bv, sc[nt]);
                }
            f4 ss[4];
            #pragma unroll
            for (int nt = 0; nt < 4; ++nt) ss[nt] = (f4)0.f;
            #pragma unroll
            for (int f = 0; f < 2; ++f)
                #pragma unroll
                for (int nt = 0; nt < 4; ++nt) {
                    s8 bv = *(const s8*)&Ksf[cur][nt * 16 + l16][f * 32 + quad * 8];
                    ss[nt] = MFMA16(qs[f], bv, ss[nt]);
                }
            #pragma unroll
            for (int reg = 0; reg < 4; ++reg) {
                const int t_g = rb + quad * 4 + reg;
                #pragma unroll
                for (int nt = 0; nt < 4; ++nt) {
                    float pv = (s0 + nt * 16 + l16 <= t_g) ? __expf(sc[nt][reg] * (1.f / 16.f)) : 0.f;
                    lc[reg] += pv;
                    Ps[wave][quad * 4 + reg][nt * 16 + l16] = bfs(pv);
                }
            }
            #pragma unroll
            for (int ks = 0; ks < 2; ++ks) {
                const short* pp = &Ps[wave][l16][ks * 32 + quad * 8];
                s4 alo = *(const s4*)pp;
                s4 ahi = *(const s4*)(pp + 4);
                s8 a;
                a[0] = alo[0]; a[1] = alo[1]; a[2] = alo[2]; a[3] = alo[3];
                a[4] = ahi[0]; a[5] = ahi[1]; a[6] = ahi[2]; a[7] = ahi[3];
                #pragma unroll
                for (int dt = 0; dt < 4; ++dt) {
                    s8 bv = *(const s8*)&Vb[cur][dt * 16 + l16][ks * 32 + quad * 8];
                    oc[dt] = MFMA16(a, bv, oc[dt]);
                }
            }
            #pragma unroll
            for (int reg = 0; reg < 4; ++reg) {
                const int t_g = rb + quad * 4 + reg;
                #pragma unroll
                for (int nt = 0; nt < 4; ++nt) {
                    float pv = (s0 + nt * 16 + l16 <= t_g) ? __expf(ss[nt][reg] * 0.125f) : 0.f;
                    ls_[reg] += pv;
                    Ps[wave][quad * 4 + reg][nt * 16 + l16] = bfs(pv);
                }
            }
            #pragma unroll
            for (int ks = 0; ks < 2; ++ks) {
                const short* pp = &Ps[wave][l16][ks * 32 + quad * 8];
                s4 alo = *(const s4*)pp;
                s4 ahi = *(const s4*)(pp + 4);
                s8 a;
                a[0] = alo[0]; a[1] = alo[1]; a[2] = alo[2]; a[3] = alo[3];
                a[4] = ahi[0]; a[5] = ahi[1]; a[6] = ahi[2]; a[7] = ahi[3];
                #pragma unroll
                for (int dt = 0; dt < 4; ++dt) {
                    s8 bv = *(const s8*)&Vb[cur][dt * 16 + l16][ks * 32 + quad * 8];
                    os_[dt] = MFMA16(a, bv, os_[dt]);
                }
            }
        }
        // write next tile into the other buffer: its readers finished at the end of
        // iteration st-1 (that barrier), so no pre-barrier is needed here.
        if (pf) {
            #pragma unroll
            for (int tl = 0; tl < 4; ++tl) {
                int g = tid + tl * 512, row = g >> 5, grp = g & 31;
                *(s8*)&Kc[nxt][row][grp * 8] = kcp[tl];
            }
            int row = tid >> 3, grp = tid & 7;
            *(s8*)&Ksf[nxt][row][grp * 8] = ksp;
            *(s8*)&Vb[nxt][row][grp * 8] = vp;
        }
        __syncthreads();   // writes to buf[nxt] visible; reads of buf[cur] retired
    }

    #pragma unroll
    for (int reg = 0; reg < 4; ++reg) {
        float l1 = lc[reg], l2 = ls_[reg];
        l1 += __shfl_xor(l1, 1); l1 += __shfl_xor(l1, 2);
        l1 += __shfl_xor(l1, 4); l1 += __shfl_xor(l1, 8);
        l2 += __shfl_xor(l2, 1); l2 += __shfl_xor(l2, 2);
        l2 += __shfl_xor(l2, 4); l2 += __shfl_xor(l2, 8);
        const float i1 = 1.f / l1, i2 = 1.f / l2;
        const int t = rb + quad * 4 + reg;
        #pragma unroll
        for (int dt = 0; dt < 4; ++dt) {
            size_t idx = (size_t)(b * T_ + t) * C_ + h * HD_ + dt * 16 + l16;
            float cv = ocv[dt][reg] + oc[dt][reg] * i1 + x[idx];
            cval_bf[idx] = __float2bfloat16(cv);
            float sv = os_[dt][reg] * i2;
            sval_bf[idx] = __float2bfloat16(sv);
        }
    }
}

// ---------------- fused dual gate GEMM + sigmoid + combine -> gated bf16 ----------------
__global__ __launch_bounds__(256) void gatefuse_kernel(
    const bf16* __restrict__ svalb, const bf16* __restrict__ cvalb,
    const bf16* __restrict__ WTgs, const bf16* __restrict__ WTgc,
    const float* __restrict__ bgs, const float* __restrict__ bgc,
    bf16* __restrict__ gated)
{
    __shared__ short Sb[128][72], Cb[128][72], W1b[64][72], W2b[64][72];
    const int tid = threadIdx.x;
    const int wave = tid >> 6, lane = tid & 63;
    const int quad = lane >> 4, l16 = lane & 15;
    const int n0 = blockIdx.y * 64, m0 = blockIdx.x * 128;
    f4 aS[2][4], aC[2][4];
    #pragma unroll
    for (int mt = 0; mt < 2; ++mt)
        #pragma unroll
        for (int nt = 0; nt < 4; ++nt) { aS[mt][nt] = (f4)0.f; aC[mt][nt] = (f4)0.f; }

    for (int k0 = 0; k0 < C_; k0 += 64) {
        #pragma unroll
        for (int tl = 0; tl < 4; ++tl) {
            int g = tid + tl * 256, row = g >> 3, grp = g & 7;
            *(s8*)&Sb[row][grp * 8] = *(const s8*)&svalb[(size_t)(m0 + row) * C_ + k0 + grp * 8];
            *(s8*)&Cb[row][grp * 8] = *(const s8*)&cvalb[(size_t)(m0 + row) * C_ + k0 + grp * 8];
        }
        #pragma unroll
        for (int tl = 0; tl < 2; ++tl) {
            int g = tid + tl * 256, n = g >> 3, grp = g & 7;
            *(s8*)&W1b[n][grp * 8] = *(const s8*)&WTgs[(size_t)(n0 + n) * C_ + k0 + grp * 8];
            *(s8*)&W2b[n][grp * 8] = *(const s8*)&WTgc[(size_t)(n0 + n) * C_ + k0 + grp * 8];
        }
        __syncthreads();
        #pragma unroll
        for (int ks = 0; ks < 2; ++ks) {
            s8 s0f = *(const s8*)&Sb[wave * 32 + l16][ks * 32 + quad * 8];
            s8 s1f = *(const s8*)&Sb[wave * 32 + 16 + l16][ks * 32 + quad * 8];
            s8 c0f = *(const s8*)&Cb[wave * 32 + l16][ks * 32 + quad * 8];
            s8 c1f = *(const s8*)&Cb[wave * 32 + 16 + l16][ks * 32 + quad * 8];
            #pragma unroll
            for (int nt = 0; nt < 4; ++nt) {
                s8 w1 = *(const s8*)&W1b[nt * 16 + l16][ks * 32 + quad * 8];
                s8 w2 = *(const s8*)&W2b[nt * 16 + l16][ks * 32 + quad * 8];
                aS[0][nt] = MFMA16(s0f, w1, aS[0][nt]);
                aS[1][nt] = MFMA16(s1f, w1, aS[1][nt]);
                aC[0][nt] = MFMA16(c0f, w2, aC[0][nt]);
                aC[1][nt] = MFMA16(c1f, w2, aC[1][nt]);
            }
        }
        __syncthreads();
    }
    #pragma unroll
    for (int mt = 0; mt < 2; ++mt)
        #pragma unroll
        for (int nt = 0; nt < 4; ++nt) {
            int col = n0 + nt * 16 + l16;
            float b1 = bgs[col], b2 = bgc[col];
            #pragma unroll
            for (int reg = 0; reg < 4; ++reg) {
                int row = m0 + wave * 32 + mt * 16 + quad * 4 + reg;
                size_t idx = (size_t)row * C_ + col;
                float gs = 1.f / (1.f + __expf(-(aS[mt][nt][reg] + b1)));
                float gc = 1.f / (1.f + __expf(-(aC[mt][nt][reg] + b2)));
                float cvv = __bfloat162float(cvalb[idx]);
                float svv = __bfloat162float(svalb[idx]);
                gated[idx] = __float2bfloat16(gs * cvv + gc * svv);
            }
        }
}

extern "C" void kernel_launch(void* const* d_in, const int* in_sizes, int n_in,
                              void* d_out, int out_size, void* d_ws, size_t ws_size,
                              hipStream_t stream)
{
    const float* x      = (const float*)d_in[0];
    const float* y      = (const float*)d_in[1];
    // d_in[2]: attn_x_mask — structurally causal tril, computed inline
    const float* Wqkv_x = (const float*)d_in[3];
    const float* bqkv_x = (const float*)d_in[4];
    const float* Wqkv_y = (const float*)d_in[5];
    const float* bqkv_y = (const float*)d_in[6];
    const float* w4x    = (const float*)d_in[7];
    const float* w4y    = (const float*)d_in[8];
    const float* w4xy   = (const float*)d_in[9];
    const float* Wgs    = (const float*)d_in[10];
    const float* bgs    = (const float*)d_in[11];
    const float* Wgc    = (const float*)d_in[12];
    const float* bgc    = (const float*)d_in[13];
    const float* Wp     = (const float*)d_in[14];
    const float* bp     = (const float*)d_in[15];

    // Workspace (f-word offsets; proven layout)
    float* ws = (float*)d_ws;
    bf16*  qkv_x_bf = (bf16*)(ws + 0);           // 6,291,456 bf16
    bf16*  qkv_y_bf = (bf16*)(ws + 3145728);     // 1,572,864 bf16
    bf16*  gated_bf = (bf16*)(ws + 3932160);
    bf16*  cval_bf  = (bf16*)(ws + 5242880);
    bf16*  x2y_bf   = (bf16*)(ws + 12320768);    // 8,388,608 bf16 (written by catt3r)
    bf16*  x_bf     = x2y_bf;                    //   pre-QKV reuse
    bf16*  y_bf     = (bf16*)(ws + 13369344);    //   pre-QKV reuse
    bf16*  y2x_bf   = (bf16*)(ws + 16515072);    // 8,388,608 bf16 (written by y2xw)
    bf16*  vTx_bf   = (bf16*)(ws + 20709376);    // 2,097,152 bf16
    bf16*  vTy_bf   = (bf16*)(ws + 21757952);    // 524,288 bf16
    float* psum_    = ws + 22020096;             // 131,072 f
    bf16*  qw_bf    = (bf16*)(ws + 26214400);    // 2,097,152 bf16 (dead after catt3r)
    bf16*  sval_bf  = qw_bf;                     //   reuse
    bf16*  WT_x     = (bf16*)(ws + 27262976);    // 786,432 bf16
    bf16*  WT_y     = (bf16*)(ws + 27656192);
    bf16*  WT_gs    = (bf16*)(ws + 28049408);    // 262,144 bf16
    bf16*  WT_gc    = (bf16*)(ws + 28180480);
    bf16*  WT_p    = (bf16*)(ws + 28311552);
    float* catt1b   = ws + 28442624;             // 32,768 f
    float* catt2b   = ws + 28475392;             //  8,192 f
    float* colinv   = ws + 28483584;             //  8,192 f
    float* rowsum_  = ws + 28491776;             // 32,768 f

    // 0: one prep dispatch
    prep_kernel<<<1856, 256, 0, stream>>>(
        Wqkv_x, Wqkv_y, Wgs, Wgc, Wp, x, y,
        WT_x, WT_y, WT_gs, WT_gc, WT_p, x_bf, y_bf);

    // 1-2: QKV projections
    gemm_staged_kernel<bf16><<<dim3(32, 24), 256, 0, stream>>>(x_bf, WT_x, bqkv_x, qkv_x_bf, C3_, C_);
    gemm_staged_kernel<bf16><<<dim3(8, 24), 256, 0, stream>>>(y_bf, WT_y, bqkv_y, qkv_y_bf, C3_, C_);

    // 3: catt1/catt2/qw
    qwcatt_kernel<<<1184, 256, 0, stream>>>(
        qkv_x_bf, qkv_y_bf, w4x, w4y, w4xy, catt1b, catt2b, qw_bf);

    // 4: fused logits + row softmax -> x2y + rowsum + col partials
    catt3r_kernel<<<dim3(32, 16), 256, 0, stream>>>(
        qw_bf, qkv_y_bf, catt1b, catt2b, x2y_bf, rowsum_, psum_);

    // 5: colfin + V transposes
    colfin_vtrans_kernel<<<672, 256, 0, stream>>>(psum_, colinv, qkv_x_bf, qkv_y_bf, vTx_bf, vTy_bf);

    // 6: y2x = x2y * rowsum * colinv
    y2xw_kernel<<<4096, 256, 0, stream>>>(x2y_bf, rowsum_, colinv, y2x_bf);

    // 7: flash8 + double-buffer + single barrier per iteration
    flash12_kernel<<<dim3(32, 8), 512, 0, stream>>>(
        x2y_bf, y2x_bf, vTx_bf, vTy_bf, qkv_x_bf, x, cval_bf, sval_bf);

    // 8: fused gates (bf16 elementwise)
    gatefuse_kernel<<<dim3(32, 8), 256, 0, stream>>>(
        sval_bf, cval_bf, WT_gs, WT_gc, bgs, bgc, gated_bf);

    // 9: out = gated @ Wp + bp
    gemm_staged_kernel<float><<<dim3(32, 8), 256, 0, stream>>>(
        gated_bf, WT_p, bp, (float*)d_out, C_, C_);
}